// Round 4
// baseline (1783.149 us; speedup 1.0000x reference)
//
#include <hip/hip_runtime.h>
#include <hip/hip_bf16.h>

typedef __hip_bfloat16 bf16;

#define NN 16384          // gate nodes
#define BBG 64            // graphs
#define EE 49152          // directed edges (no self loops)
#define ET (EE + NN)      // edges + self loops = 65536
#define DD 512            // node feature dim (2F)
#define NG (NN / BBG)     // 256 nodes per graph
#define MAXDEG 96
#define STAGE_CAP 16      // xl rows staged in LDS (deg max ~15 for Poisson(3))

__device__ __forceinline__ float b2f(bf16 v) { return __bfloat162float(v); }
__device__ __forceinline__ bf16 f2b(float v) { return __float2bfloat16(v); }
__device__ __forceinline__ int clampi(int v, int lo, int hi)
{
    return v < lo ? lo : (v > hi ? hi : v);
}

typedef __attribute__((ext_vector_type(8))) short bf16x8;  // 8 bf16 = 4 VGPRs
typedef __attribute__((ext_vector_type(4))) float f32x4;

#define AS1 __attribute__((address_space(1)))
#define AS3 __attribute__((address_space(3)))

// ---------------------------------------------------------------------------
// MFMA bf16 GEMM (m97 structure): C[M,N] = act(A[M,K] @ Bt[N,K]^T + bias).
// 128x128 tile, BK=32, 256 threads (4 waves, 2x2), 4x4 16x16x32 frags/wave.
// ---------------------------------------------------------------------------
__global__ __launch_bounds__(256) void gemm_mfma_bt(
    const bf16* __restrict__ A, const bf16* __restrict__ Bt,
    const float* __restrict__ bias, float* __restrict__ C,
    bf16* __restrict__ Cb, int M, int N, int K, float slope, int has_act)
{
    __shared__ bf16 As[128 * 32];
    __shared__ bf16 Bs[128 * 32];
    const int tid = threadIdx.x;
    const int w = tid >> 6;
    const int l = tid & 63;
    const int bm = blockIdx.y * 128;
    const int bn = blockIdx.x * 128;
    const int wrow = (w >> 1) * 64;
    const int wcol = (w & 1) * 64;
    const int quad = l >> 4;
    const int c16 = l & 15;

    const int lrow = l >> 2;
    const int lchunk = l & 3;
    const bf16* Ag = A + (size_t)(bm + w * 16 + lrow) * K + lchunk * 8;
    const bf16* Bg = Bt + (size_t)(bn + w * 16 + lrow) * K + lchunk * 8;
    char* AsB = (char*)As;
    char* BsB = (char*)Bs;

    f32x4 acc[4][4] = {};

    for (int k0 = 0; k0 < K; k0 += 32) {
        __builtin_amdgcn_global_load_lds((const AS1 void*)(Ag + k0),
            (AS3 void*)(AsB + w * 1024), 16, 0, 0);
        __builtin_amdgcn_global_load_lds((const AS1 void*)(Ag + (size_t)64 * K + k0),
            (AS3 void*)(AsB + 4096 + w * 1024), 16, 0, 0);
        __builtin_amdgcn_global_load_lds((const AS1 void*)(Bg + k0),
            (AS3 void*)(BsB + w * 1024), 16, 0, 0);
        __builtin_amdgcn_global_load_lds((const AS1 void*)(Bg + (size_t)64 * K + k0),
            (AS3 void*)(BsB + 4096 + w * 1024), 16, 0, 0);
        __syncthreads();

        bf16x8 a[4], b[4];
#pragma unroll
        for (int i = 0; i < 4; i++) {
            int ra = wrow + i * 16 + c16;
            a[i] = *(const bf16x8*)(AsB + ra * 64 + quad * 16);
            int rb = wcol + i * 16 + c16;
            b[i] = *(const bf16x8*)(BsB + rb * 64 + quad * 16);
        }
#pragma unroll
        for (int i = 0; i < 4; i++)
#pragma unroll
            for (int j = 0; j < 4; j++)
                acc[i][j] = __builtin_amdgcn_mfma_f32_16x16x32_bf16(
                    a[i], b[j], acc[i][j], 0, 0, 0);
        __syncthreads();
    }

#pragma unroll
    for (int i = 0; i < 4; i++) {
#pragma unroll
        for (int j = 0; j < 4; j++) {
            int col = bn + wcol + j * 16 + c16;
            float bv = bias ? bias[col] : 0.f;
#pragma unroll
            for (int r = 0; r < 4; r++) {
                int row = bm + wrow + i * 16 + quad * 4 + r;
                float v = acc[i][j][r] + bv;
                if (has_act) v = (v >= 0.f) ? v : v * slope;
                if (C)  C[(size_t)row * N + col] = v;
                if (Cb) Cb[(size_t)row * N + col] = f2b(v);
            }
        }
    }
}

// ---------------------------------------------------------------------------
// fp32 GEMM (head MLP only)
// ---------------------------------------------------------------------------
__global__ __launch_bounds__(256) void gemm_f32(
    const float* __restrict__ A, const float* __restrict__ W,
    const float* __restrict__ bias, float* __restrict__ C,
    int M, int N, int K, float slope, int has_act)
{
    const int BK = 16;
    __shared__ float Asm[BK][64 + 1];
    __shared__ float Wsm[BK][64 + 1];
    int tid = threadIdx.x;
    int bm = blockIdx.y * 64;
    int bn = blockIdx.x * 64;
    int tr = tid >> 4;
    int tc = tid & 15;
    float acc[4][4] = {};

    for (int k0 = 0; k0 < K; k0 += BK) {
        {
            int col = tid & 15;
            int row = tid >> 4;
#pragma unroll
            for (int p = 0; p < 4; p++) {
                int r = row + p * 16;
                Asm[col][r] = A[(size_t)(bm + r) * K + k0 + col];
            }
        }
        {
            int wc = tid & 63;
            int wr = tid >> 6;
#pragma unroll
            for (int p = 0; p < 4; p++) {
                int r = wr + p * 4;
                Wsm[r][wc] = W[(size_t)(k0 + r) * N + bn + wc];
            }
        }
        __syncthreads();
#pragma unroll
        for (int kk = 0; kk < BK; kk++) {
            float a[4], w[4];
#pragma unroll
            for (int i = 0; i < 4; i++) a[i] = Asm[kk][tr * 4 + i];
#pragma unroll
            for (int j = 0; j < 4; j++) w[j] = Wsm[kk][tc * 4 + j];
#pragma unroll
            for (int i = 0; i < 4; i++)
#pragma unroll
                for (int j = 0; j < 4; j++)
                    acc[i][j] += a[i] * w[j];
        }
        __syncthreads();
    }
#pragma unroll
    for (int i = 0; i < 4; i++) {
        int r = bm + tr * 4 + i;
#pragma unroll
        for (int j = 0; j < 4; j++) {
            int cn = bn + tc * 4 + j;
            float v = acc[i][j];
            if (bias) v += bias[cn];
            if (has_act) v = (v >= 0.f) ? v : v * slope;
            C[(size_t)r * N + cn] = v;
        }
    }
}

// ---------------------------------------------------------------------------
// Batched fp32 [R,C] -> bf16 [C,R] transpose-convert (z selects tensor pair)
// ---------------------------------------------------------------------------
__global__ __launch_bounds__(256) void transpose_f2b2(
    const float* __restrict__ in0, bf16* __restrict__ out0,
    const float* __restrict__ in1, bf16* __restrict__ out1, int R, int C)
{
    const float* in = blockIdx.z ? in1 : in0;
    bf16* out = blockIdx.z ? out1 : out0;
    __shared__ float tile[32][33];
    int c0 = blockIdx.x * 32;
    int r0 = blockIdx.y * 32;
    int tx = threadIdx.x & 31;
    int ty = threadIdx.x >> 5;
#pragma unroll
    for (int k = 0; k < 4; k++) {
        int r = ty + k * 8;
        tile[r][tx] = in[(size_t)(r0 + r) * C + c0 + tx];
    }
    __syncthreads();
#pragma unroll
    for (int k = 0; k < 4; k++) {
        int rr = ty + k * 8;
        out[(size_t)(c0 + rr) * R + r0 + tx] = f2b(tile[tx][rr]);
    }
}

__global__ void f2b_vec(const float* __restrict__ in, bf16* __restrict__ out, int n)
{
    int i = blockIdx.x * 256 + threadIdx.x;
    if (i < n) out[i] = f2b(in[i]);
}

// ---------------------------------------------------------------------------
// CSR build over dst (self loops: edge ids [EE, ET) are node e-EE)
// ---------------------------------------------------------------------------
__global__ void count_deg(const int* __restrict__ ei, int* __restrict__ deg)
{
    int e = blockIdx.x * 256 + threadIdx.x;
    if (e >= ET) return;
    int d = (e < EE) ? ei[EE + e] : (e - EE);
    d = clampi(d, 0, NN - 1);
    atomicAdd(&deg[d], 1);
}

__global__ __launch_bounds__(256) void scan_deg(const int* __restrict__ deg,
                                                int* __restrict__ rs)
{
    __shared__ int part[256];
    __shared__ int psum[257];
    int tid = threadIdx.x;
    const int per = NN / 256;
    int base = tid * per;
    int s = 0;
    for (int i = 0; i < per; i++) s += deg[base + i];
    part[tid] = s;
    __syncthreads();
    if (tid == 0) {
        int acc = 0;
        for (int i = 0; i < 256; i++) { psum[i] = acc; acc += part[i]; }
        psum[256] = acc;
    }
    __syncthreads();
    int acc = psum[tid];
    for (int i = 0; i < per; i++) { rs[base + i] = acc; acc += deg[base + i]; }
    if (tid == 0) rs[NN] = psum[256];
}

__global__ void fill_csr(const int* __restrict__ ei, const int* __restrict__ rs,
                         int* __restrict__ cur, int* __restrict__ csrc)
{
    int e = blockIdx.x * 256 + threadIdx.x;
    if (e >= ET) return;
    int s, d;
    if (e < EE) { s = ei[e]; d = ei[EE + e]; } else { s = d = e - EE; }
    s = clampi(s, 0, NN - 1);
    d = clampi(d, 0, NN - 1);
    int pos = atomicAdd(&cur[d], 1);
    int slot = clampi(rs[d] + pos, 0, ET - 1);
    csrc[slot] = s;
}

// ---------------------------------------------------------------------------
// Fused GATv2 edge phase: one block per node. Computes in-edge logits
// (wave-per-edge dot), softmax, and aggregation. Stages xl[src] rows in LDS
// (up to STAGE_CAP) so each gathered row is read from global exactly once.
// Optionally accumulates per-graph sum/sum^2 of the output (for LayerNorm).
// ---------------------------------------------------------------------------
__global__ __launch_bounds__(256) void gat_fused(
    const bf16* __restrict__ xl, const bf16* __restrict__ xr,
    const float* __restrict__ att, const float* __restrict__ bias,
    const int* __restrict__ rs, const int* __restrict__ csrc,
    const float* __restrict__ res, float* __restrict__ out_f,
    bf16* __restrict__ out_b, float* __restrict__ lnsums, int H, int HC)
{
    __shared__ bf16 s_xr[1024];
    __shared__ bf16 s_stage[STAGE_CAP][1024];
    __shared__ float s_logit[MAXDEG][2];
    __shared__ float s_alpha[MAXDEG][2];
    __shared__ int s_src[MAXDEG];
    __shared__ float s_red[256], s_red2[256];

    const int n = blockIdx.x;
    const int tid = threadIdx.x;
    const int w = tid >> 6;
    const int lane = tid & 63;
    int start = rs[n];
    int deg = clampi(rs[n + 1] - start, 1, MAXDEG);
    start = clampi(start, 0, ET - 1);
    const int stage = deg < STAGE_CAP ? deg : STAGE_CAP;

    if (tid < deg) s_src[tid] = clampi(csrc[start + tid], 0, NN - 1);
    for (int c = tid; c < HC; c += 256) s_xr[c] = xr[(size_t)n * HC + c];
    __syncthreads();   // s_src ready before staging uses it

    // stage xl rows as 8B chunks (coalesced, one chunk/thread for HC=1024)
    const int nch = HC >> 2;
    for (int i = 0; i < stage; i++) {
        const uint2* src8 = (const uint2*)(xl + (size_t)s_src[i] * HC);
        uint2* dst8 = (uint2*)(&s_stage[i][0]);
        for (int c = tid; c < nch; c += 256) dst8[c] = src8[c];
    }
    __syncthreads();

    // logits: wave per edge; att flat [H*DD] == [HC]
    for (int i = w; i < deg; i += 4) {
        const bf16* grow = xl + (size_t)s_src[i] * HC;
        float a0 = 0.f, a1 = 0.f;
        for (int c = lane; c < HC; c += 64) {
            float xv = (i < STAGE_CAP) ? b2f(s_stage[i][c]) : b2f(grow[c]);
            float v = xv + b2f(s_xr[c]);
            v = (v >= 0.f) ? v : 0.2f * v;
            float av = att[c];
            if (c < DD) a0 += av * v; else a1 += av * v;
        }
#pragma unroll
        for (int off = 32; off; off >>= 1) {
            a0 += __shfl_down(a0, off);
            a1 += __shfl_down(a1, off);
        }
        if (lane == 0) { s_logit[i][0] = a0; s_logit[i][1] = a1; }
    }
    __syncthreads();

    if (tid < H) {
        float m = -1e30f;
        for (int i = 0; i < deg; i++) m = fmaxf(m, s_logit[i][tid]);
        float den = 0.f;
        for (int i = 0; i < deg; i++) {
            float pp = __expf(s_logit[i][tid] - m);
            s_alpha[i][tid] = pp;
            den += pp;
        }
        float inv = 1.f / den;
        for (int i = 0; i < deg; i++) s_alpha[i][tid] *= inv;
    }
    __syncthreads();

    float ls = 0.f, ls2 = 0.f;
    for (int c = tid; c < HC; c += 256) {
        int h = c >> 9;           // c / DD
        float acc = bias[c];
        for (int i = 0; i < deg; i++) {
            float xv = (i < STAGE_CAP) ? b2f(s_stage[i][c])
                                       : b2f(xl[(size_t)s_src[i] * HC + c]);
            acc += s_alpha[i][h] * xv;
        }
        acc = (acc >= 0.f) ? acc : 0.01f * acc;
        if (res) acc += res[(size_t)n * HC + c];
        if (out_f) out_f[(size_t)n * HC + c] = acc;
        if (out_b) out_b[(size_t)n * HC + c] = f2b(acc);
        ls += acc; ls2 += acc * acc;
    }

    if (lnsums) {   // per-graph LN partial sums (L4 only)
        s_red[tid] = ls; s_red2[tid] = ls2;
        __syncthreads();
        for (int o = 128; o; o >>= 1) {
            if (tid < o) { s_red[tid] += s_red[tid + o]; s_red2[tid] += s_red2[tid + o]; }
            __syncthreads();
        }
        if (tid == 0) {
            int g = n >> 8;       // NG = 256 nodes per graph
            atomicAdd(&lnsums[g], s_red[0]);
            atomicAdd(&lnsums[BBG + g], s_red2[0]);
        }
    }
}

// ---------------------------------------------------------------------------
// LN apply + channel-wise online-softmax aggregation, node-chunked partials.
// grid (BBG, 2, 4): graph g, channel half, 64-node chunk. Single data pass.
// ---------------------------------------------------------------------------
__global__ __launch_bounds__(256) void aggr_partial(
    const float* __restrict__ h, const float* __restrict__ lnsums,
    const float* __restrict__ lnw, const float* __restrict__ lnb,
    const float* __restrict__ t_, float* __restrict__ pm,
    float* __restrict__ pd, float* __restrict__ pa)
{
    int g = blockIdx.x, ch = blockIdx.y, nk = blockIdx.z;
    int tid = threadIdx.x;
    int c = ch * 256 + tid;
    const float tot = (float)(NG * DD);
    float S = lnsums[g], S2 = lnsums[BBG + g];
    float mu = S / tot;
    float iv = rsqrtf(fmaxf(S2 / tot - mu * mu, 0.f) + 1e-5f);
    float w = lnw[c], b = lnb[c], t = t_[0];
    size_t base = (size_t)g * NG * DD + (size_t)nk * 64 * DD + c;
    float m = -1e30f, den = 0.f, acc = 0.f;
    for (int i = 0; i < 64; i++) {
        float hn = (h[base + (size_t)i * DD] - mu) * iv * w + b;
        float lg = hn * t;
        if (lg > m) {
            float r = __expf(m - lg);
            den *= r; acc *= r; m = lg;
        }
        float p = __expf(lg - m);
        den += p; acc += p * hn;
    }
    size_t idx = (((size_t)g * 2 + ch) * 4 + nk) * 256 + tid;
    pm[idx] = m; pd[idx] = den; pa[idx] = acc;
}

__global__ __launch_bounds__(256) void aggr_combine(
    const float* __restrict__ pm, const float* __restrict__ pd,
    const float* __restrict__ pa, float* __restrict__ gout)
{
    int g = blockIdx.x, ch = blockIdx.y;
    int tid = threadIdx.x;
    size_t base = (((size_t)g * 2 + ch) * 4) * 256 + tid;
    float m = -1e30f;
#pragma unroll
    for (int k = 0; k < 4; k++) m = fmaxf(m, pm[base + k * 256]);
    float den = 0.f, acc = 0.f;
#pragma unroll
    for (int k = 0; k < 4; k++) {
        float r = __expf(pm[base + k * 256] - m);
        den += pd[base + k * 256] * r;
        acc += pa[base + k * 256] * r;
    }
    gout[(size_t)g * DD + ch * 256 + tid] = acc / den;
}

// ---------------------------------------------------------------------------
extern "C" void kernel_launch(void* const* d_in, const int* in_sizes, int n_in,
                              void* d_out, int out_size, void* d_ws, size_t ws_size,
                              hipStream_t stream)
{
    const float* x      = (const float*)d_in[0];
    const int*   ei     = (const int*)d_in[1];
    const float* xt_w1  = (const float*)d_in[3];
    const float* xt_b1  = (const float*)d_in[4];
    const float* xt_w2  = (const float*)d_in[5];
    const float* xt_b2  = (const float*)d_in[6];
    const float* ln_w   = (const float*)d_in[27];
    const float* ln_b   = (const float*)d_in[28];
    const float* aggr_t = (const float*)d_in[29];
    const float* m_w1   = (const float*)d_in[30];
    const float* m_b1   = (const float*)d_in[31];
    const float* m_w2   = (const float*)d_in[32];
    const float* m_b2   = (const float*)d_in[33];
    const float* m_w3   = (const float*)d_in[34];
    const float* m_b3   = (const float*)d_in[35];
    float* out = (float*)d_out;

    // ---- workspace layout (256B aligned); ints first ----
    char* p = (char*)d_ws;
    auto take = [&](size_t bytes) {
        char* r = p;
        p += (bytes + 255) & ~(size_t)255;
        return r;
    };
    int* i_deg     = (int*)take((size_t)(NN + 1) * 4);
    int* i_rs      = (int*)take((size_t)(NN + 1) * 4);
    int* i_cur     = (int*)take((size_t)NN * 4);
    int* i_src     = (int*)take((size_t)ET * 4);
    float* f_sums  = (float*)take((size_t)2 * BBG * 4);       // LN sum / sum^2
    float* f_pm    = (float*)take((size_t)BBG * 2 * 4 * 256 * 4);
    float* f_pd    = (float*)take((size_t)BBG * 2 * 4 * 256 * 4);
    float* f_pa    = (float*)take((size_t)BBG * 2 * 4 * 256 * 4);
    float* b_g     = (float*)take((size_t)BBG * DD * 4);
    float* b_m1    = (float*)take((size_t)BBG * 384 * 4);
    float* b_m2    = (float*)take((size_t)BBG * 256 * 4);
    float* b_res   = (float*)take((size_t)NN * DD * 4);       // fp32 residual
    float* b_h     = (float*)take((size_t)NN * DD * 4);       // fp32 final h
    bf16* b_resb   = (bf16*)take((size_t)NN * DD * 2);        // bf16 cx
    bf16* b_hb     = (bf16*)take((size_t)NN * 1024 * 2);      // bf16 h (alias t1b)
    bf16* b_xlb    = (bf16*)take((size_t)NN * 1024 * 2);
    bf16* b_xrb    = (bf16*)take((size_t)NN * 1024 * 2);
    bf16* b_xb     = (bf16*)take((size_t)2 * NN * 32 * 2);
    bf16* b_wlb    = (bf16*)take((size_t)1024 * 1024 * 2);
    bf16* b_wrb    = (bf16*)take((size_t)1024 * 1024 * 2);
    bf16* b_w1b    = (bf16*)take((size_t)32 * 256 * 2);
    bf16* b_w2b    = (bf16*)take((size_t)256 * 256 * 2);
    bf16* b_t1b = b_hb;

    dim3 blk(256);

    // ---- CSR build + LN-sum zero ----
    hipMemsetAsync(i_deg, 0, (size_t)(NN + 1) * 4, stream);
    hipMemsetAsync(i_cur, 0, (size_t)NN * 4, stream);
    hipMemsetAsync(f_sums, 0, (size_t)2 * BBG * 4, stream);
    count_deg<<<ET / 256, blk, 0, stream>>>(ei, i_deg);
    scan_deg<<<1, blk, 0, stream>>>(i_deg, i_rs);
    fill_csr<<<ET / 256, blk, 0, stream>>>(ei, i_rs, i_cur, i_src);

    // ---- weight converts for x_trans + x convert ----
    f2b_vec<<<(2 * NN * 32 + 255) / 256, blk, 0, stream>>>(x, b_xb, 2 * NN * 32);
    transpose_f2b2<<<dim3(256 / 32, 32 / 32, 1), blk, 0, stream>>>(
        xt_w1, b_w1b, xt_w1, b_w1b, 32, 256);
    transpose_f2b2<<<dim3(256 / 32, 256 / 32, 1), blk, 0, stream>>>(
        xt_w2, b_w2b, xt_w2, b_w2b, 256, 256);

    // ---- x_trans ----
    gemm_mfma_bt<<<dim3(256 / 128, 32768 / 128), blk, 0, stream>>>(
        b_xb, b_w1b, xt_b1, (float*)nullptr, b_t1b, 32768, 256, 32, 0.01f, 1);
    gemm_mfma_bt<<<dim3(256 / 128, 32768 / 128), blk, 0, stream>>>(
        b_t1b, b_w2b, xt_b2, b_res, b_resb, 32768, 256, 256, 0.f, 0);

    // ---- 5 GATv2 layers ----
    for (int L = 0; L < 5; L++) {
        const float* wl  = (const float*)d_in[7 + 4 * L];
        const float* wr  = (const float*)d_in[8 + 4 * L];
        const float* att = (const float*)d_in[9 + 4 * L];
        const float* gb  = (const float*)d_in[10 + 4 * L];
        int Fin = (L == 0) ? 512 : 1024;
        int H   = (L == 4) ? 1 : 2;
        int HC  = H * DD;
        const bf16* hin = (L == 0) ? b_resb : b_hb;

        transpose_f2b2<<<dim3(HC / 32, Fin / 32, 2), blk, 0, stream>>>(
            wl, b_wlb, wr, b_wrb, Fin, HC);
        gemm_mfma_bt<<<dim3(HC / 128, NN / 128), blk, 0, stream>>>(
            hin, b_wlb, (const float*)nullptr, (float*)nullptr, b_xlb,
            NN, HC, Fin, 0.f, 0);
        gemm_mfma_bt<<<dim3(HC / 128, NN / 128), blk, 0, stream>>>(
            hin, b_wrb, (const float*)nullptr, (float*)nullptr, b_xrb,
            NN, HC, Fin, 0.f, 0);
        gat_fused<<<NN, blk, 0, stream>>>(
            b_xlb, b_xrb, att, gb, i_rs, i_src,
            (L == 4) ? b_res : (const float*)nullptr,
            (L == 4) ? b_h : (float*)nullptr,
            (L == 4) ? (bf16*)nullptr : b_hb,
            (L == 4) ? f_sums : (float*)nullptr, H, HC);
    }

    // ---- graph LN + softmax aggregation (single pass + combine) ----
    aggr_partial<<<dim3(BBG, 2, 4), blk, 0, stream>>>(
        b_h, f_sums, ln_w, ln_b, aggr_t, f_pm, f_pd, f_pa);
    aggr_combine<<<dim3(BBG, 2), blk, 0, stream>>>(f_pm, f_pd, f_pa, b_g);

    // ---- head MLP 512 -> 384 -> 256 -> 128 (fp32) ----
    gemm_f32<<<dim3(384 / 64, 1), blk, 0, stream>>>(
        b_g, m_w1, m_b1, b_m1, 64, 384, 512, 0.01f, 1);
    gemm_f32<<<dim3(256 / 64, 1), blk, 0, stream>>>(
        b_m1, m_w2, m_b2, b_m2, 64, 256, 384, 0.01f, 1);
    gemm_f32<<<dim3(128 / 64, 1), blk, 0, stream>>>(
        b_m2, m_w3, m_b3, out, 64, 128, 256, 0.f, 0);
}

// Round 5
// 1220.075 us; speedup vs baseline: 1.4615x; 1.4615x over previous
//
#include <hip/hip_runtime.h>
#include <hip/hip_bf16.h>

typedef __hip_bfloat16 bf16;

#define NN 16384          // gate nodes
#define BBG 64            // graphs
#define EE 49152          // directed edges (no self loops)
#define ET (EE + NN)      // edges + self loops = 65536
#define DD 512            // node feature dim (2F)
#define NG (NN / BBG)     // 256 nodes per graph
#define MAXDEG 96

__device__ __forceinline__ float b2f(bf16 v) { return __bfloat162float(v); }
__device__ __forceinline__ bf16 f2b(float v) { return __float2bfloat16(v); }
__device__ __forceinline__ float sb2f(short s) {
    unsigned u = ((unsigned)(unsigned short)s) << 16;
    return __builtin_bit_cast(float, u);
}
__device__ __forceinline__ short f2bs(float v) {
    bf16 b = f2b(v);
    return __builtin_bit_cast(short, b);
}
__device__ __forceinline__ int clampi(int v, int lo, int hi)
{
    return v < lo ? lo : (v > hi ? hi : v);
}

typedef __attribute__((ext_vector_type(8))) short bf16x8;  // 8 bf16 = 4 VGPRs
typedef __attribute__((ext_vector_type(4))) short short4v; // 4 bf16 = 8 B
typedef __attribute__((ext_vector_type(2))) short short2v; // 2 bf16 = 4 B
typedef __attribute__((ext_vector_type(4))) float f32x4;

#define AS1 __attribute__((address_space(1)))
#define AS3 __attribute__((address_space(3)))

// ---------------------------------------------------------------------------
// MFMA bf16 GEMM (m97 structure): C[M,N] = act(A[M,K] @ Bt[N,K]^T + bias).
// 128x128 tile, BK=32, 256 threads (4 waves, 2x2), 4x4 16x16x32 frags/wave.
// ---------------------------------------------------------------------------
__global__ __launch_bounds__(256) void gemm_mfma_bt(
    const bf16* __restrict__ A, const bf16* __restrict__ Bt,
    const float* __restrict__ bias, float* __restrict__ C,
    bf16* __restrict__ Cb, int M, int N, int K, float slope, int has_act)
{
    __shared__ bf16 As[128 * 32];
    __shared__ bf16 Bs[128 * 32];
    const int tid = threadIdx.x;
    const int w = tid >> 6;
    const int l = tid & 63;
    const int bm = blockIdx.y * 128;
    const int bn = blockIdx.x * 128;
    const int wrow = (w >> 1) * 64;
    const int wcol = (w & 1) * 64;
    const int quad = l >> 4;
    const int c16 = l & 15;

    const int lrow = l >> 2;
    const int lchunk = l & 3;
    const bf16* Ag = A + (size_t)(bm + w * 16 + lrow) * K + lchunk * 8;
    const bf16* Bg = Bt + (size_t)(bn + w * 16 + lrow) * K + lchunk * 8;
    char* AsB = (char*)As;
    char* BsB = (char*)Bs;

    f32x4 acc[4][4] = {};

    for (int k0 = 0; k0 < K; k0 += 32) {
        __builtin_amdgcn_global_load_lds((const AS1 void*)(Ag + k0),
            (AS3 void*)(AsB + w * 1024), 16, 0, 0);
        __builtin_amdgcn_global_load_lds((const AS1 void*)(Ag + (size_t)64 * K + k0),
            (AS3 void*)(AsB + 4096 + w * 1024), 16, 0, 0);
        __builtin_amdgcn_global_load_lds((const AS1 void*)(Bg + k0),
            (AS3 void*)(BsB + w * 1024), 16, 0, 0);
        __builtin_amdgcn_global_load_lds((const AS1 void*)(Bg + (size_t)64 * K + k0),
            (AS3 void*)(BsB + 4096 + w * 1024), 16, 0, 0);
        __syncthreads();

        bf16x8 a[4], b[4];
#pragma unroll
        for (int i = 0; i < 4; i++) {
            int ra = wrow + i * 16 + c16;
            a[i] = *(const bf16x8*)(AsB + ra * 64 + quad * 16);
            int rb = wcol + i * 16 + c16;
            b[i] = *(const bf16x8*)(BsB + rb * 64 + quad * 16);
        }
#pragma unroll
        for (int i = 0; i < 4; i++)
#pragma unroll
            for (int j = 0; j < 4; j++)
                acc[i][j] = __builtin_amdgcn_mfma_f32_16x16x32_bf16(
                    a[i], b[j], acc[i][j], 0, 0, 0);
        __syncthreads();
    }

#pragma unroll
    for (int i = 0; i < 4; i++) {
#pragma unroll
        for (int j = 0; j < 4; j++) {
            int col = bn + wcol + j * 16 + c16;
            float bv = bias ? bias[col] : 0.f;
#pragma unroll
            for (int r = 0; r < 4; r++) {
                int row = bm + wrow + i * 16 + quad * 4 + r;
                float v = acc[i][j][r] + bv;
                if (has_act) v = (v >= 0.f) ? v : v * slope;
                if (C)  C[(size_t)row * N + col] = v;
                if (Cb) Cb[(size_t)row * N + col] = f2b(v);
            }
        }
    }
}

// ---------------------------------------------------------------------------
// fp32 GEMM (head MLP only)
// ---------------------------------------------------------------------------
__global__ __launch_bounds__(256) void gemm_f32(
    const float* __restrict__ A, const float* __restrict__ W,
    const float* __restrict__ bias, float* __restrict__ C,
    int M, int N, int K, float slope, int has_act)
{
    const int BK = 16;
    __shared__ float Asm[BK][64 + 1];
    __shared__ float Wsm[BK][64 + 1];
    int tid = threadIdx.x;
    int bm = blockIdx.y * 64;
    int bn = blockIdx.x * 64;
    int tr = tid >> 4;
    int tc = tid & 15;
    float acc[4][4] = {};

    for (int k0 = 0; k0 < K; k0 += BK) {
        {
            int col = tid & 15;
            int row = tid >> 4;
#pragma unroll
            for (int p = 0; p < 4; p++) {
                int r = row + p * 16;
                Asm[col][r] = A[(size_t)(bm + r) * K + k0 + col];
            }
        }
        {
            int wc = tid & 63;
            int wr = tid >> 6;
#pragma unroll
            for (int p = 0; p < 4; p++) {
                int r = wr + p * 4;
                Wsm[r][wc] = W[(size_t)(k0 + r) * N + bn + wc];
            }
        }
        __syncthreads();
#pragma unroll
        for (int kk = 0; kk < BK; kk++) {
            float a[4], w[4];
#pragma unroll
            for (int i = 0; i < 4; i++) a[i] = Asm[kk][tr * 4 + i];
#pragma unroll
            for (int j = 0; j < 4; j++) w[j] = Wsm[kk][tc * 4 + j];
#pragma unroll
            for (int i = 0; i < 4; i++)
#pragma unroll
                for (int j = 0; j < 4; j++)
                    acc[i][j] += a[i] * w[j];
        }
        __syncthreads();
    }
#pragma unroll
    for (int i = 0; i < 4; i++) {
        int r = bm + tr * 4 + i;
#pragma unroll
        for (int j = 0; j < 4; j++) {
            int cn = bn + tc * 4 + j;
            float v = acc[i][j];
            if (bias) v += bias[cn];
            if (has_act) v = (v >= 0.f) ? v : v * slope;
            C[(size_t)r * N + cn] = v;
        }
    }
}

// ---------------------------------------------------------------------------
// Batched fp32 [R,C] -> bf16 [C,R] transpose-convert (z selects tensor pair)
// ---------------------------------------------------------------------------
__global__ __launch_bounds__(256) void transpose_f2b2(
    const float* __restrict__ in0, bf16* __restrict__ out0,
    const float* __restrict__ in1, bf16* __restrict__ out1, int R, int C)
{
    const float* in = blockIdx.z ? in1 : in0;
    bf16* out = blockIdx.z ? out1 : out0;
    __shared__ float tile[32][33];
    int c0 = blockIdx.x * 32;
    int r0 = blockIdx.y * 32;
    int tx = threadIdx.x & 31;
    int ty = threadIdx.x >> 5;
#pragma unroll
    for (int k = 0; k < 4; k++) {
        int r = ty + k * 8;
        tile[r][tx] = in[(size_t)(r0 + r) * C + c0 + tx];
    }
    __syncthreads();
#pragma unroll
    for (int k = 0; k < 4; k++) {
        int rr = ty + k * 8;
        out[(size_t)(c0 + rr) * R + r0 + tx] = f2b(tile[tx][rr]);
    }
}

__global__ void f2b_vec(const float* __restrict__ in, bf16* __restrict__ out, int n)
{
    int i = blockIdx.x * 256 + threadIdx.x;
    if (i < n) out[i] = f2b(in[i]);
}

// ---------------------------------------------------------------------------
// CSR build over dst (self loops: edge ids [EE, ET) are node e-EE)
// ---------------------------------------------------------------------------
__global__ void count_deg(const int* __restrict__ ei, int* __restrict__ deg)
{
    int e = blockIdx.x * 256 + threadIdx.x;
    if (e >= ET) return;
    int d = (e < EE) ? ei[EE + e] : (e - EE);
    d = clampi(d, 0, NN - 1);
    atomicAdd(&deg[d], 1);
}

__global__ __launch_bounds__(256) void scan_deg(const int* __restrict__ deg,
                                                int* __restrict__ rs)
{
    __shared__ int part[256];
    __shared__ int psum[257];
    int tid = threadIdx.x;
    const int per = NN / 256;
    int base = tid * per;
    int s = 0;
    for (int i = 0; i < per; i++) s += deg[base + i];
    part[tid] = s;
    __syncthreads();
    if (tid == 0) {
        int acc = 0;
        for (int i = 0; i < 256; i++) { psum[i] = acc; acc += part[i]; }
        psum[256] = acc;
    }
    __syncthreads();
    int acc = psum[tid];
    for (int i = 0; i < per; i++) { rs[base + i] = acc; acc += deg[base + i]; }
    if (tid == 0) rs[NN] = psum[256];
}

__global__ void fill_csr(const int* __restrict__ ei, const int* __restrict__ rs,
                         int* __restrict__ cur, int* __restrict__ csrc)
{
    int e = blockIdx.x * 256 + threadIdx.x;
    if (e >= ET) return;
    int s, d;
    if (e < EE) { s = ei[e]; d = ei[EE + e]; } else { s = d = e - EE; }
    s = clampi(s, 0, NN - 1);
    d = clampi(d, 0, NN - 1);
    int pos = atomicAdd(&cur[d], 1);
    int slot = clampi(rs[d] + pos, 0, ET - 1);
    csrc[slot] = s;
}

// ---------------------------------------------------------------------------
// Fused GATv2 edge phase v2: one block per node, NO LDS staging (gathered
// rows are L2-resident; staging only cost occupancy — round-4 lesson).
// Phase 1: wave-per-edge logits, att+xr preloaded to registers, bf16x8 loads.
// Phase 2: softmax (2 threads). Phase 3: 4-ch-per-thread aggregation with
// 8B gathered loads and packed stores. Optional per-graph LN sums.
// ---------------------------------------------------------------------------
__global__ __launch_bounds__(256) void gat_fused2(
    const bf16* __restrict__ xl, const bf16* __restrict__ xr,
    const float* __restrict__ att, const float* __restrict__ bias,
    const int* __restrict__ rs, const int* __restrict__ csrc,
    const float* __restrict__ res, float* __restrict__ out_f,
    bf16* __restrict__ out_b, float* __restrict__ lnsums, int HC)
{
    __shared__ float s_logit[MAXDEG][2];
    __shared__ float s_alpha[MAXDEG][2];
    __shared__ int s_src[MAXDEG];
    __shared__ float s_red[256], s_red2[256];

    const int n = blockIdx.x;
    const int tid = threadIdx.x;
    const int w = tid >> 6;
    const int lane = tid & 63;
    int start = rs[n];
    int deg = clampi(rs[n + 1] - start, 1, MAXDEG);
    start = clampi(start, 0, ET - 1);
    if (tid < deg) s_src[tid] = clampi(csrc[start + tid], 0, NN - 1);
    __syncthreads();

    // ---- phase 1: logits ----
    if (HC == 1024) {
        const int c0 = lane * 16;      // lanes 0..31 head0, 32..63 head1
        float av[16], rv[16];
        {
            bf16x8 r0 = *(const bf16x8*)(xr + (size_t)n * HC + c0);
            bf16x8 r1 = *(const bf16x8*)(xr + (size_t)n * HC + c0 + 8);
#pragma unroll
            for (int k = 0; k < 8; k++) { rv[k] = sb2f(r0[k]); rv[8 + k] = sb2f(r1[k]); }
#pragma unroll
            for (int k = 0; k < 16; k++) av[k] = att[c0 + k];
        }
        for (int i = w; i < deg; i += 4) {
            const bf16* row = xl + (size_t)s_src[i] * HC + c0;
            bf16x8 v0 = *(const bf16x8*)(row);
            bf16x8 v1 = *(const bf16x8*)(row + 8);
            float acc = 0.f;
#pragma unroll
            for (int k = 0; k < 8; k++) {
                float u = sb2f(v0[k]) + rv[k];
                u = (u >= 0.f) ? u : 0.2f * u;
                acc += av[k] * u;
                float u2 = sb2f(v1[k]) + rv[8 + k];
                u2 = (u2 >= 0.f) ? u2 : 0.2f * u2;
                acc += av[8 + k] * u2;
            }
#pragma unroll
            for (int off = 16; off; off >>= 1) acc += __shfl_down(acc, off);
            if (lane == 0) s_logit[i][0] = acc;    // sum of lanes 0..31
            if (lane == 32) s_logit[i][1] = acc;   // sum of lanes 32..63
        }
    } else {   // HC == 512, single head
        const int c0 = lane * 8;
        float av[8], rv[8];
        bf16x8 r0 = *(const bf16x8*)(xr + (size_t)n * HC + c0);
#pragma unroll
        for (int k = 0; k < 8; k++) { rv[k] = sb2f(r0[k]); av[k] = att[c0 + k]; }
        for (int i = w; i < deg; i += 4) {
            bf16x8 v0 = *(const bf16x8*)(xl + (size_t)s_src[i] * HC + c0);
            float acc = 0.f;
#pragma unroll
            for (int k = 0; k < 8; k++) {
                float u = sb2f(v0[k]) + rv[k];
                u = (u >= 0.f) ? u : 0.2f * u;
                acc += av[k] * u;
            }
#pragma unroll
            for (int off = 32; off; off >>= 1) acc += __shfl_down(acc, off);
            if (lane == 0) s_logit[i][0] = acc;
        }
    }
    __syncthreads();

    // ---- phase 2: softmax over in-edges (per head) ----
    const int H = (HC == 1024) ? 2 : 1;
    if (tid < H) {
        float m = -1e30f;
        for (int i = 0; i < deg; i++) m = fmaxf(m, s_logit[i][tid]);
        float den = 0.f;
        for (int i = 0; i < deg; i++) {
            float pp = __expf(s_logit[i][tid] - m);
            s_alpha[i][tid] = pp;
            den += pp;
        }
        float inv = 1.f / den;
        for (int i = 0; i < deg; i++) s_alpha[i][tid] *= inv;
    }
    __syncthreads();

    // ---- phase 3: aggregation ----
    float ls = 0.f, ls2 = 0.f;
    if (HC == 1024) {
        const int c0 = tid * 4;
        const int h = c0 >> 9;
        float a0 = bias[c0], a1 = bias[c0 + 1], a2 = bias[c0 + 2], a3 = bias[c0 + 3];
        for (int i = 0; i < deg; i++) {
            float al = s_alpha[i][h];
            short4v v = *(const short4v*)(xl + (size_t)s_src[i] * HC + c0);
            a0 += al * sb2f(v[0]);
            a1 += al * sb2f(v[1]);
            a2 += al * sb2f(v[2]);
            a3 += al * sb2f(v[3]);
        }
        a0 = (a0 >= 0.f) ? a0 : 0.01f * a0;
        a1 = (a1 >= 0.f) ? a1 : 0.01f * a1;
        a2 = (a2 >= 0.f) ? a2 : 0.01f * a2;
        a3 = (a3 >= 0.f) ? a3 : 0.01f * a3;
        short4v ov;
        ov[0] = f2bs(a0); ov[1] = f2bs(a1); ov[2] = f2bs(a2); ov[3] = f2bs(a3);
        *(short4v*)(out_b + (size_t)n * HC + c0) = ov;
        ls = a0 + a1 + a2 + a3;
        ls2 = a0 * a0 + a1 * a1 + a2 * a2 + a3 * a3;
    } else {
        const int c0 = tid * 2;
        float a0 = bias[c0], a1 = bias[c0 + 1];
        for (int i = 0; i < deg; i++) {
            float al = s_alpha[i][0];
            short2v v = *(const short2v*)(xl + (size_t)s_src[i] * HC + c0);
            a0 += al * sb2f(v[0]);
            a1 += al * sb2f(v[1]);
        }
        a0 = (a0 >= 0.f) ? a0 : 0.01f * a0;
        a1 = (a1 >= 0.f) ? a1 : 0.01f * a1;
        if (res) {
            const float2 rv = *(const float2*)(res + (size_t)n * HC + c0);
            a0 += rv.x; a1 += rv.y;
        }
        *(float2*)(out_f + (size_t)n * HC + c0) = make_float2(a0, a1);
        ls = a0 + a1;
        ls2 = a0 * a0 + a1 * a1;
    }

    if (lnsums) {   // per-graph LN partial sums (L4 only)
        s_red[tid] = ls; s_red2[tid] = ls2;
        __syncthreads();
        for (int o = 128; o; o >>= 1) {
            if (tid < o) { s_red[tid] += s_red[tid + o]; s_red2[tid] += s_red2[tid + o]; }
            __syncthreads();
        }
        if (tid == 0) {
            int g = n >> 8;
            atomicAdd(&lnsums[g], s_red[0]);
            atomicAdd(&lnsums[BBG + g], s_red2[0]);
        }
    }
}

// ---------------------------------------------------------------------------
// LN apply + channel-wise online-softmax aggregation, node-chunked partials.
// ---------------------------------------------------------------------------
__global__ __launch_bounds__(256) void aggr_partial(
    const float* __restrict__ h, const float* __restrict__ lnsums,
    const float* __restrict__ lnw, const float* __restrict__ lnb,
    const float* __restrict__ t_, float* __restrict__ pm,
    float* __restrict__ pd, float* __restrict__ pa)
{
    int g = blockIdx.x, ch = blockIdx.y, nk = blockIdx.z;
    int tid = threadIdx.x;
    int c = ch * 256 + tid;
    const float tot = (float)(NG * DD);
    float S = lnsums[g], S2 = lnsums[BBG + g];
    float mu = S / tot;
    float iv = rsqrtf(fmaxf(S2 / tot - mu * mu, 0.f) + 1e-5f);
    float w = lnw[c], b = lnb[c], t = t_[0];
    size_t base = (size_t)g * NG * DD + (size_t)nk * 64 * DD + c;
    float m = -1e30f, den = 0.f, acc = 0.f;
    for (int i = 0; i < 64; i++) {
        float hn = (h[base + (size_t)i * DD] - mu) * iv * w + b;
        float lg = hn * t;
        if (lg > m) {
            float r = __expf(m - lg);
            den *= r; acc *= r; m = lg;
        }
        float p = __expf(lg - m);
        den += p; acc += p * hn;
    }
    size_t idx = (((size_t)g * 2 + ch) * 4 + nk) * 256 + tid;
    pm[idx] = m; pd[idx] = den; pa[idx] = acc;
}

__global__ __launch_bounds__(256) void aggr_combine(
    const float* __restrict__ pm, const float* __restrict__ pd,
    const float* __restrict__ pa, float* __restrict__ gout)
{
    int g = blockIdx.x, ch = blockIdx.y;
    int tid = threadIdx.x;
    size_t base = (((size_t)g * 2 + ch) * 4) * 256 + tid;
    float m = -1e30f;
#pragma unroll
    for (int k = 0; k < 4; k++) m = fmaxf(m, pm[base + k * 256]);
    float den = 0.f, acc = 0.f;
#pragma unroll
    for (int k = 0; k < 4; k++) {
        float r = __expf(pm[base + k * 256] - m);
        den += pd[base + k * 256] * r;
        acc += pa[base + k * 256] * r;
    }
    gout[(size_t)g * DD + ch * 256 + tid] = acc / den;
}

// ---------------------------------------------------------------------------
extern "C" void kernel_launch(void* const* d_in, const int* in_sizes, int n_in,
                              void* d_out, int out_size, void* d_ws, size_t ws_size,
                              hipStream_t stream)
{
    const float* x      = (const float*)d_in[0];
    const int*   ei     = (const int*)d_in[1];
    const float* xt_w1  = (const float*)d_in[3];
    const float* xt_b1  = (const float*)d_in[4];
    const float* xt_w2  = (const float*)d_in[5];
    const float* xt_b2  = (const float*)d_in[6];
    const float* ln_w   = (const float*)d_in[27];
    const float* ln_b   = (const float*)d_in[28];
    const float* aggr_t = (const float*)d_in[29];
    const float* m_w1   = (const float*)d_in[30];
    const float* m_b1   = (const float*)d_in[31];
    const float* m_w2   = (const float*)d_in[32];
    const float* m_b2   = (const float*)d_in[33];
    const float* m_w3   = (const float*)d_in[34];
    const float* m_b3   = (const float*)d_in[35];
    float* out = (float*)d_out;

    // ---- workspace layout (256B aligned); ints first ----
    char* p = (char*)d_ws;
    auto take = [&](size_t bytes) {
        char* r = p;
        p += (bytes + 255) & ~(size_t)255;
        return r;
    };
    int* i_deg     = (int*)take((size_t)(NN + 1) * 4);
    int* i_rs      = (int*)take((size_t)(NN + 1) * 4);
    int* i_cur     = (int*)take((size_t)NN * 4);
    int* i_src     = (int*)take((size_t)ET * 4);
    float* f_sums  = (float*)take((size_t)2 * BBG * 4);
    float* f_pm    = (float*)take((size_t)BBG * 2 * 4 * 256 * 4);
    float* f_pd    = (float*)take((size_t)BBG * 2 * 4 * 256 * 4);
    float* f_pa    = (float*)take((size_t)BBG * 2 * 4 * 256 * 4);
    float* b_g     = (float*)take((size_t)BBG * DD * 4);
    float* b_m1    = (float*)take((size_t)BBG * 384 * 4);
    float* b_m2    = (float*)take((size_t)BBG * 256 * 4);
    float* b_res   = (float*)take((size_t)NN * DD * 4);
    float* b_h     = (float*)take((size_t)NN * DD * 4);
    bf16* b_resb   = (bf16*)take((size_t)NN * DD * 2);
    bf16* b_hb     = (bf16*)take((size_t)NN * 1024 * 2);
    bf16* b_xlb    = (bf16*)take((size_t)NN * 1024 * 2);
    bf16* b_xrb    = (bf16*)take((size_t)NN * 1024 * 2);
    bf16* b_xb     = (bf16*)take((size_t)2 * NN * 32 * 2);
    bf16* b_wlb    = (bf16*)take((size_t)1024 * 1024 * 2);
    bf16* b_wrb    = (bf16*)take((size_t)1024 * 1024 * 2);
    bf16* b_w1b    = (bf16*)take((size_t)32 * 256 * 2);
    bf16* b_w2b    = (bf16*)take((size_t)256 * 256 * 2);
    bf16* b_t1b = b_hb;

    dim3 blk(256);

    // ---- CSR build + LN-sum zero ----
    hipMemsetAsync(i_deg, 0, (size_t)(NN + 1) * 4, stream);
    hipMemsetAsync(i_cur, 0, (size_t)NN * 4, stream);
    hipMemsetAsync(f_sums, 0, (size_t)2 * BBG * 4, stream);
    count_deg<<<ET / 256, blk, 0, stream>>>(ei, i_deg);
    scan_deg<<<1, blk, 0, stream>>>(i_deg, i_rs);
    fill_csr<<<ET / 256, blk, 0, stream>>>(ei, i_rs, i_cur, i_src);

    // ---- weight converts for x_trans + x convert ----
    f2b_vec<<<(2 * NN * 32 + 255) / 256, blk, 0, stream>>>(x, b_xb, 2 * NN * 32);
    transpose_f2b2<<<dim3(256 / 32, 32 / 32, 1), blk, 0, stream>>>(
        xt_w1, b_w1b, xt_w1, b_w1b, 32, 256);
    transpose_f2b2<<<dim3(256 / 32, 256 / 32, 1), blk, 0, stream>>>(
        xt_w2, b_w2b, xt_w2, b_w2b, 256, 256);

    // ---- x_trans ----
    gemm_mfma_bt<<<dim3(256 / 128, 32768 / 128), blk, 0, stream>>>(
        b_xb, b_w1b, xt_b1, (float*)nullptr, b_t1b, 32768, 256, 32, 0.01f, 1);
    gemm_mfma_bt<<<dim3(256 / 128, 32768 / 128), blk, 0, stream>>>(
        b_t1b, b_w2b, xt_b2, b_res, b_resb, 32768, 256, 256, 0.f, 0);

    // ---- 5 GATv2 layers ----
    for (int L = 0; L < 5; L++) {
        const float* wl  = (const float*)d_in[7 + 4 * L];
        const float* wr  = (const float*)d_in[8 + 4 * L];
        const float* att = (const float*)d_in[9 + 4 * L];
        const float* gb  = (const float*)d_in[10 + 4 * L];
        int Fin = (L == 0) ? 512 : 1024;
        int HC  = (L == 4) ? 512 : 1024;
        const bf16* hin = (L == 0) ? b_resb : b_hb;

        transpose_f2b2<<<dim3(HC / 32, Fin / 32, 2), blk, 0, stream>>>(
            wl, b_wlb, wr, b_wrb, Fin, HC);
        gemm_mfma_bt<<<dim3(HC / 128, NN / 128), blk, 0, stream>>>(
            hin, b_wlb, (const float*)nullptr, (float*)nullptr, b_xlb,
            NN, HC, Fin, 0.f, 0);
        gemm_mfma_bt<<<dim3(HC / 128, NN / 128), blk, 0, stream>>>(
            hin, b_wrb, (const float*)nullptr, (float*)nullptr, b_xrb,
            NN, HC, Fin, 0.f, 0);
        gat_fused2<<<NN, blk, 0, stream>>>(
            b_xlb, b_xrb, att, gb, i_rs, i_src,
            (L == 4) ? b_res : (const float*)nullptr,
            (L == 4) ? b_h : (float*)nullptr,
            (L == 4) ? (bf16*)nullptr : b_hb,
            (L == 4) ? f_sums : (float*)nullptr, HC);
    }

    // ---- graph LN + softmax aggregation (single pass + combine) ----
    aggr_partial<<<dim3(BBG, 2, 4), blk, 0, stream>>>(
        b_h, f_sums, ln_w, ln_b, aggr_t, f_pm, f_pd, f_pa);
    aggr_combine<<<dim3(BBG, 2), blk, 0, stream>>>(f_pm, f_pd, f_pa, b_g);

    // ---- head MLP 512 -> 384 -> 256 -> 128 (fp32) ----
    gemm_f32<<<dim3(384 / 64, 1), blk, 0, stream>>>(
        b_g, m_w1, m_b1, b_m1, 64, 384, 512, 0.01f, 1);
    gemm_f32<<<dim3(256 / 64, 1), blk, 0, stream>>>(
        b_m1, m_w2, m_b2, b_m2, 64, 256, 384, 0.01f, 1);
    gemm_f32<<<dim3(128 / 64, 1), blk, 0, stream>>>(
        b_m2, m_w3, m_b3, out, 64, 128, 256, 0.f, 0);
}

// Round 6
// 1161.878 us; speedup vs baseline: 1.5347x; 1.0501x over previous
//
#include <hip/hip_runtime.h>
#include <hip/hip_bf16.h>

typedef __hip_bfloat16 bf16;

#define NN 16384          // gate nodes
#define BBG 64            // graphs
#define EE 49152          // directed edges (no self loops)
#define ET (EE + NN)      // edges + self loops = 65536
#define DD 512            // node feature dim (2F)
#define NG (NN / BBG)     // 256 nodes per graph

__device__ __forceinline__ float b2f(bf16 v) { return __bfloat162float(v); }
__device__ __forceinline__ bf16 f2b(float v) { return __float2bfloat16(v); }
__device__ __forceinline__ float sb2f(short s) {
    unsigned u = ((unsigned)(unsigned short)s) << 16;
    return __builtin_bit_cast(float, u);
}
__device__ __forceinline__ short f2bs(float v) {
    bf16 b = f2b(v);
    return __builtin_bit_cast(short, b);
}
__device__ __forceinline__ int clampi(int v, int lo, int hi)
{
    return v < lo ? lo : (v > hi ? hi : v);
}

typedef __attribute__((ext_vector_type(8))) short bf16x8;  // 8 bf16 = 4 VGPRs
typedef __attribute__((ext_vector_type(4))) float f32x4;

#define AS1 __attribute__((address_space(1)))
#define AS3 __attribute__((address_space(3)))

// ---------------------------------------------------------------------------
// MFMA bf16 GEMM (m97 structure): C[M,N] = act(A[M,K] @ Bt[N,K]^T + bias).
// ---------------------------------------------------------------------------
__global__ __launch_bounds__(256) void gemm_mfma_bt(
    const bf16* __restrict__ A, const bf16* __restrict__ Bt,
    const float* __restrict__ bias, float* __restrict__ C,
    bf16* __restrict__ Cb, int M, int N, int K, float slope, int has_act)
{
    __shared__ bf16 As[128 * 32];
    __shared__ bf16 Bs[128 * 32];
    const int tid = threadIdx.x;
    const int w = tid >> 6;
    const int l = tid & 63;
    const int bm = blockIdx.y * 128;
    const int bn = blockIdx.x * 128;
    const int wrow = (w >> 1) * 64;
    const int wcol = (w & 1) * 64;
    const int quad = l >> 4;
    const int c16 = l & 15;

    const int lrow = l >> 2;
    const int lchunk = l & 3;
    const bf16* Ag = A + (size_t)(bm + w * 16 + lrow) * K + lchunk * 8;
    const bf16* Bg = Bt + (size_t)(bn + w * 16 + lrow) * K + lchunk * 8;
    char* AsB = (char*)As;
    char* BsB = (char*)Bs;

    f32x4 acc[4][4] = {};

    for (int k0 = 0; k0 < K; k0 += 32) {
        __builtin_amdgcn_global_load_lds((const AS1 void*)(Ag + k0),
            (AS3 void*)(AsB + w * 1024), 16, 0, 0);
        __builtin_amdgcn_global_load_lds((const AS1 void*)(Ag + (size_t)64 * K + k0),
            (AS3 void*)(AsB + 4096 + w * 1024), 16, 0, 0);
        __builtin_amdgcn_global_load_lds((const AS1 void*)(Bg + k0),
            (AS3 void*)(BsB + w * 1024), 16, 0, 0);
        __builtin_amdgcn_global_load_lds((const AS1 void*)(Bg + (size_t)64 * K + k0),
            (AS3 void*)(BsB + 4096 + w * 1024), 16, 0, 0);
        __syncthreads();

        bf16x8 a[4], b[4];
#pragma unroll
        for (int i = 0; i < 4; i++) {
            int ra = wrow + i * 16 + c16;
            a[i] = *(const bf16x8*)(AsB + ra * 64 + quad * 16);
            int rb = wcol + i * 16 + c16;
            b[i] = *(const bf16x8*)(BsB + rb * 64 + quad * 16);
        }
#pragma unroll
        for (int i = 0; i < 4; i++)
#pragma unroll
            for (int j = 0; j < 4; j++)
                acc[i][j] = __builtin_amdgcn_mfma_f32_16x16x32_bf16(
                    a[i], b[j], acc[i][j], 0, 0, 0);
        __syncthreads();
    }

#pragma unroll
    for (int i = 0; i < 4; i++) {
#pragma unroll
        for (int j = 0; j < 4; j++) {
            int col = bn + wcol + j * 16 + c16;
            float bv = bias ? bias[col] : 0.f;
#pragma unroll
            for (int r = 0; r < 4; r++) {
                int row = bm + wrow + i * 16 + quad * 4 + r;
                float v = acc[i][j][r] + bv;
                if (has_act) v = (v >= 0.f) ? v : v * slope;
                if (C)  C[(size_t)row * N + col] = v;
                if (Cb) Cb[(size_t)row * N + col] = f2b(v);
            }
        }
    }
}

// ---------------------------------------------------------------------------
// fp32 GEMM (head MLP only)
// ---------------------------------------------------------------------------
__global__ __launch_bounds__(256) void gemm_f32(
    const float* __restrict__ A, const float* __restrict__ W,
    const float* __restrict__ bias, float* __restrict__ C,
    int M, int N, int K, float slope, int has_act)
{
    const int BK = 16;
    __shared__ float Asm[BK][64 + 1];
    __shared__ float Wsm[BK][64 + 1];
    int tid = threadIdx.x;
    int bm = blockIdx.y * 64;
    int bn = blockIdx.x * 64;
    int tr = tid >> 4;
    int tc = tid & 15;
    float acc[4][4] = {};

    for (int k0 = 0; k0 < K; k0 += BK) {
        {
            int col = tid & 15;
            int row = tid >> 4;
#pragma unroll
            for (int p = 0; p < 4; p++) {
                int r = row + p * 16;
                Asm[col][r] = A[(size_t)(bm + r) * K + k0 + col];
            }
        }
        {
            int wc = tid & 63;
            int wr = tid >> 6;
#pragma unroll
            for (int p = 0; p < 4; p++) {
                int r = wr + p * 4;
                Wsm[r][wc] = W[(size_t)(k0 + r) * N + bn + wc];
            }
        }
        __syncthreads();
#pragma unroll
        for (int kk = 0; kk < BK; kk++) {
            float a[4], w[4];
#pragma unroll
            for (int i = 0; i < 4; i++) a[i] = Asm[kk][tr * 4 + i];
#pragma unroll
            for (int j = 0; j < 4; j++) w[j] = Wsm[kk][tc * 4 + j];
#pragma unroll
            for (int i = 0; i < 4; i++)
#pragma unroll
                for (int j = 0; j < 4; j++)
                    acc[i][j] += a[i] * w[j];
        }
        __syncthreads();
    }
#pragma unroll
    for (int i = 0; i < 4; i++) {
        int r = bm + tr * 4 + i;
#pragma unroll
        for (int j = 0; j < 4; j++) {
            int cn = bn + tc * 4 + j;
            float v = acc[i][j];
            if (bias) v += bias[cn];
            if (has_act) v = (v >= 0.f) ? v : v * slope;
            C[(size_t)r * N + cn] = v;
        }
    }
}

// ---------------------------------------------------------------------------
// Batched fp32 [R,C] -> bf16 [C,R] transpose-convert (z selects tensor pair)
// ---------------------------------------------------------------------------
__global__ __launch_bounds__(256) void transpose_f2b2(
    const float* __restrict__ in0, bf16* __restrict__ out0,
    const float* __restrict__ in1, bf16* __restrict__ out1, int R, int C)
{
    const float* in = blockIdx.z ? in1 : in0;
    bf16* out = blockIdx.z ? out1 : out0;
    __shared__ float tile[32][33];
    int c0 = blockIdx.x * 32;
    int r0 = blockIdx.y * 32;
    int tx = threadIdx.x & 31;
    int ty = threadIdx.x >> 5;
#pragma unroll
    for (int k = 0; k < 4; k++) {
        int r = ty + k * 8;
        tile[r][tx] = in[(size_t)(r0 + r) * C + c0 + tx];
    }
    __syncthreads();
#pragma unroll
    for (int k = 0; k < 4; k++) {
        int rr = ty + k * 8;
        out[(size_t)(c0 + rr) * R + r0 + tx] = f2b(tile[tx][rr]);
    }
}

__global__ void f2b_vec(const float* __restrict__ in, bf16* __restrict__ out, int n)
{
    int i = blockIdx.x * 256 + threadIdx.x;
    if (i < n) out[i] = f2b(in[i]);
}

// ---------------------------------------------------------------------------
// CSR build over dst (self loops: edge ids [EE, ET) are node e-EE)
// ---------------------------------------------------------------------------
__global__ void count_deg(const int* __restrict__ ei, int* __restrict__ deg)
{
    int e = blockIdx.x * 256 + threadIdx.x;
    if (e >= ET) return;
    int d = (e < EE) ? ei[EE + e] : (e - EE);
    d = clampi(d, 0, NN - 1);
    atomicAdd(&deg[d], 1);
}

__global__ __launch_bounds__(256) void scan_deg(const int* __restrict__ deg,
                                                int* __restrict__ rs)
{
    __shared__ int part[256];
    __shared__ int psum[257];
    int tid = threadIdx.x;
    const int per = NN / 256;
    int base = tid * per;
    int s = 0;
    for (int i = 0; i < per; i++) s += deg[base + i];
    part[tid] = s;
    __syncthreads();
    if (tid == 0) {
        int acc = 0;
        for (int i = 0; i < 256; i++) { psum[i] = acc; acc += part[i]; }
        psum[256] = acc;
    }
    __syncthreads();
    int acc = psum[tid];
    for (int i = 0; i < per; i++) { rs[base + i] = acc; acc += deg[base + i]; }
    if (tid == 0) rs[NN] = psum[256];
}

__global__ void fill_csr(const int* __restrict__ ei, const int* __restrict__ rs,
                         int* __restrict__ cur, int* __restrict__ csrc)
{
    int e = blockIdx.x * 256 + threadIdx.x;
    if (e >= ET) return;
    int s, d;
    if (e < EE) { s = ei[e]; d = ei[EE + e]; } else { s = d = e - EE; }
    s = clampi(s, 0, NN - 1);
    d = clampi(d, 0, NN - 1);
    int pos = atomicAdd(&cur[d], 1);
    int slot = clampi(rs[d] + pos, 0, ET - 1);
    csrc[slot] = s;
}

// ---------------------------------------------------------------------------
// GATv2 edge phase v3: ONE WAVE PER NODE, zero barriers, zero LDS.
// Single pass over gathered rows with online softmax (flash-style m/den/acc).
// HC=1024: lanes 0..31 = head0 (ch 0..511), 32..63 = head1; 16 ch/lane.
// HC=512:  single head, 8 ch/lane. Butterfly __shfl_xor reduce per head-half.
// Depth-3 row prefetch for memory-level parallelism.
// ---------------------------------------------------------------------------
template<int HC>
__global__ __launch_bounds__(256) void gat_wave(
    const bf16* __restrict__ xl, const bf16* __restrict__ xr,
    const float* __restrict__ att, const float* __restrict__ bias,
    const int* __restrict__ rs, const int* __restrict__ csrc,
    const float* __restrict__ res, float* __restrict__ out_f,
    bf16* __restrict__ out_b, float* __restrict__ lnsums)
{
    constexpr int CPL = HC / 64;     // channels per lane (16 or 8)
    constexpr int NV = CPL / 8;      // bf16x8 vectors per lane (2 or 1)
    const int tid = threadIdx.x;
    const int w = tid >> 6;
    const int lane = tid & 63;
    const int n = blockIdx.x * 4 + w;
    const int c0 = lane * CPL;

    int start = rs[n];
    int deg = clampi(rs[n + 1] - start, 1, 64);
    start = clampi(start, 0, ET - 1);
    int my_src = 0;
    if (lane < deg) my_src = clampi(csrc[start + lane], 0, NN - 1);

    // preload att + xr chunk into registers (reused across all edges)
    float av[CPL], rv[CPL];
    {
        bf16x8 rp[NV];
#pragma unroll
        for (int v = 0; v < NV; v++)
            rp[v] = *(const bf16x8*)(xr + (size_t)n * HC + c0 + v * 8);
#pragma unroll
        for (int k = 0; k < CPL; k++) {
            rv[k] = sb2f(rp[k / 8][k % 8]);
            av[k] = att[c0 + k];
        }
    }

    float m = -1e30f, den = 0.f;
    float acc[CPL];
#pragma unroll
    for (int k = 0; k < CPL; k++) acc[k] = 0.f;

    auto loadrow = [&](int i, bf16x8* dst) {
        int s = __shfl(my_src, i);
        const bf16* rp = xl + (size_t)s * HC + c0;
#pragma unroll
        for (int v = 0; v < NV; v++) dst[v] = *(const bf16x8*)(rp + v * 8);
    };

    bf16x8 cur[NV], nx1[NV], nx2[NV];
    loadrow(0, cur);
    if (deg > 1) loadrow(1, nx1);
    if (deg > 2) loadrow(2, nx2);

    for (int i = 0; i < deg; i++) {
        bf16x8 nxt[NV];
        if (i + 3 < deg) loadrow(i + 3, nxt);

        // logit partial for this lane's channels
        float part = 0.f;
#pragma unroll
        for (int k = 0; k < CPL; k++) {
            float x = sb2f(cur[k / 8][k % 8]);
            float u = x + rv[k];
            u = (u >= 0.f) ? u : 0.2f * u;
            part = fmaf(av[k], u, part);
        }
        // butterfly reduce within head-half; every lane gets its head's logit
        if (HC == 1024) {
#pragma unroll
            for (int msk = 16; msk; msk >>= 1) part += __shfl_xor(part, msk);
        } else {
#pragma unroll
            for (int msk = 32; msk; msk >>= 1) part += __shfl_xor(part, msk);
        }
        float lg = part;

        // online softmax update
        float mn = fmaxf(m, lg);
        float r = __expf(m - mn);
        float pi = __expf(lg - mn);
        m = mn;
        den = den * r + pi;
#pragma unroll
        for (int k = 0; k < CPL; k++) {
            float x = sb2f(cur[k / 8][k % 8]);
            acc[k] = fmaf(acc[k], r, pi * x);
        }
#pragma unroll
        for (int v = 0; v < NV; v++) { cur[v] = nx1[v]; nx1[v] = nx2[v]; nx2[v] = nxt[v]; }
    }

    float inv = 1.f / den;
    float ls = 0.f, ls2 = 0.f;
    float vals[CPL];
#pragma unroll
    for (int k = 0; k < CPL; k++) {
        float v = fmaf(acc[k], inv, bias[c0 + k]);
        v = (v >= 0.f) ? v : 0.01f * v;
        vals[k] = v;
    }
    if (res) {   // L4: residual add, fp32 out, LN sums
#pragma unroll
        for (int k = 0; k < CPL; k++) {
            vals[k] += res[(size_t)n * HC + c0 + k];
            ls += vals[k];
            ls2 += vals[k] * vals[k];
        }
#pragma unroll
        for (int v = 0; v < NV * 2; v++) {
            f32x4 ov;
#pragma unroll
            for (int k = 0; k < 4; k++) ov[k] = vals[v * 4 + k];
            *(f32x4*)(out_f + (size_t)n * HC + c0 + v * 4) = ov;
        }
    } else {     // L0-3: bf16 out
#pragma unroll
        for (int v = 0; v < NV; v++) {
            bf16x8 ov;
#pragma unroll
            for (int k = 0; k < 8; k++) ov[k] = f2bs(vals[v * 8 + k]);
            *(bf16x8*)(out_b + (size_t)n * HC + c0 + v * 8) = ov;
        }
    }

    if (lnsums) {   // wave butterfly + one atomic pair per node
#pragma unroll
        for (int msk = 32; msk; msk >>= 1) {
            ls += __shfl_xor(ls, msk);
            ls2 += __shfl_xor(ls2, msk);
        }
        if (lane == 0) {
            int g = n >> 8;
            atomicAdd(&lnsums[g], ls);
            atomicAdd(&lnsums[BBG + g], ls2);
        }
    }
}

// ---------------------------------------------------------------------------
// LN apply + channel-wise online-softmax aggregation, node-chunked partials.
// ---------------------------------------------------------------------------
__global__ __launch_bounds__(256) void aggr_partial(
    const float* __restrict__ h, const float* __restrict__ lnsums,
    const float* __restrict__ lnw, const float* __restrict__ lnb,
    const float* __restrict__ t_, float* __restrict__ pm,
    float* __restrict__ pd, float* __restrict__ pa)
{
    int g = blockIdx.x, ch = blockIdx.y, nk = blockIdx.z;
    int tid = threadIdx.x;
    int c = ch * 256 + tid;
    const float tot = (float)(NG * DD);
    float S = lnsums[g], S2 = lnsums[BBG + g];
    float mu = S / tot;
    float iv = rsqrtf(fmaxf(S2 / tot - mu * mu, 0.f) + 1e-5f);
    float w = lnw[c], b = lnb[c], t = t_[0];
    size_t base = (size_t)g * NG * DD + (size_t)nk * 64 * DD + c;
    float m = -1e30f, den = 0.f, acc = 0.f;
    for (int i = 0; i < 64; i++) {
        float hn = (h[base + (size_t)i * DD] - mu) * iv * w + b;
        float lg = hn * t;
        if (lg > m) {
            float r = __expf(m - lg);
            den *= r; acc *= r; m = lg;
        }
        float p = __expf(lg - m);
        den += p; acc += p * hn;
    }
    size_t idx = (((size_t)g * 2 + ch) * 4 + nk) * 256 + tid;
    pm[idx] = m; pd[idx] = den; pa[idx] = acc;
}

__global__ __launch_bounds__(256) void aggr_combine(
    const float* __restrict__ pm, const float* __restrict__ pd,
    const float* __restrict__ pa, float* __restrict__ gout)
{
    int g = blockIdx.x, ch = blockIdx.y;
    int tid = threadIdx.x;
    size_t base = (((size_t)g * 2 + ch) * 4) * 256 + tid;
    float m = -1e30f;
#pragma unroll
    for (int k = 0; k < 4; k++) m = fmaxf(m, pm[base + k * 256]);
    float den = 0.f, acc = 0.f;
#pragma unroll
    for (int k = 0; k < 4; k++) {
        float r = __expf(pm[base + k * 256] - m);
        den += pd[base + k * 256] * r;
        acc += pa[base + k * 256] * r;
    }
    gout[(size_t)g * DD + ch * 256 + tid] = acc / den;
}

// ---------------------------------------------------------------------------
extern "C" void kernel_launch(void* const* d_in, const int* in_sizes, int n_in,
                              void* d_out, int out_size, void* d_ws, size_t ws_size,
                              hipStream_t stream)
{
    const float* x      = (const float*)d_in[0];
    const int*   ei     = (const int*)d_in[1];
    const float* xt_w1  = (const float*)d_in[3];
    const float* xt_b1  = (const float*)d_in[4];
    const float* xt_w2  = (const float*)d_in[5];
    const float* xt_b2  = (const float*)d_in[6];
    const float* ln_w   = (const float*)d_in[27];
    const float* ln_b   = (const float*)d_in[28];
    const float* aggr_t = (const float*)d_in[29];
    const float* m_w1   = (const float*)d_in[30];
    const float* m_b1   = (const float*)d_in[31];
    const float* m_w2   = (const float*)d_in[32];
    const float* m_b2   = (const float*)d_in[33];
    const float* m_w3   = (const float*)d_in[34];
    const float* m_b3   = (const float*)d_in[35];
    float* out = (float*)d_out;

    // ---- workspace layout (256B aligned); ints first ----
    char* p = (char*)d_ws;
    auto take = [&](size_t bytes) {
        char* r = p;
        p += (bytes + 255) & ~(size_t)255;
        return r;
    };
    int* i_deg     = (int*)take((size_t)(NN + 1) * 4);
    int* i_rs      = (int*)take((size_t)(NN + 1) * 4);
    int* i_cur     = (int*)take((size_t)NN * 4);
    int* i_src     = (int*)take((size_t)ET * 4);
    float* f_sums  = (float*)take((size_t)2 * BBG * 4);
    float* f_pm    = (float*)take((size_t)BBG * 2 * 4 * 256 * 4);
    float* f_pd    = (float*)take((size_t)BBG * 2 * 4 * 256 * 4);
    float* f_pa    = (float*)take((size_t)BBG * 2 * 4 * 256 * 4);
    float* b_g     = (float*)take((size_t)BBG * DD * 4);
    float* b_m1    = (float*)take((size_t)BBG * 384 * 4);
    float* b_m2    = (float*)take((size_t)BBG * 256 * 4);
    float* b_res   = (float*)take((size_t)NN * DD * 4);
    float* b_h     = (float*)take((size_t)NN * DD * 4);
    bf16* b_resb   = (bf16*)take((size_t)NN * DD * 2);
    bf16* b_hb     = (bf16*)take((size_t)NN * 1024 * 2);
    bf16* b_xlb    = (bf16*)take((size_t)NN * 1024 * 2);
    bf16* b_xrb    = (bf16*)take((size_t)NN * 1024 * 2);
    bf16* b_xb     = (bf16*)take((size_t)2 * NN * 32 * 2);
    bf16* b_wlb    = (bf16*)take((size_t)1024 * 1024 * 2);
    bf16* b_wrb    = (bf16*)take((size_t)1024 * 1024 * 2);
    bf16* b_w1b    = (bf16*)take((size_t)32 * 256 * 2);
    bf16* b_w2b    = (bf16*)take((size_t)256 * 256 * 2);
    bf16* b_t1b = b_hb;

    dim3 blk(256);

    // ---- CSR build + LN-sum zero ----
    hipMemsetAsync(i_deg, 0, (size_t)(NN + 1) * 4, stream);
    hipMemsetAsync(i_cur, 0, (size_t)NN * 4, stream);
    hipMemsetAsync(f_sums, 0, (size_t)2 * BBG * 4, stream);
    count_deg<<<ET / 256, blk, 0, stream>>>(ei, i_deg);
    scan_deg<<<1, blk, 0, stream>>>(i_deg, i_rs);
    fill_csr<<<ET / 256, blk, 0, stream>>>(ei, i_rs, i_cur, i_src);

    // ---- weight converts for x_trans + x convert ----
    f2b_vec<<<(2 * NN * 32 + 255) / 256, blk, 0, stream>>>(x, b_xb, 2 * NN * 32);
    transpose_f2b2<<<dim3(256 / 32, 32 / 32, 1), blk, 0, stream>>>(
        xt_w1, b_w1b, xt_w1, b_w1b, 32, 256);
    transpose_f2b2<<<dim3(256 / 32, 256 / 32, 1), blk, 0, stream>>>(
        xt_w2, b_w2b, xt_w2, b_w2b, 256, 256);

    // ---- x_trans ----
    gemm_mfma_bt<<<dim3(256 / 128, 32768 / 128), blk, 0, stream>>>(
        b_xb, b_w1b, xt_b1, (float*)nullptr, b_t1b, 32768, 256, 32, 0.01f, 1);
    gemm_mfma_bt<<<dim3(256 / 128, 32768 / 128), blk, 0, stream>>>(
        b_t1b, b_w2b, xt_b2, b_res, b_resb, 32768, 256, 256, 0.f, 0);

    // ---- 5 GATv2 layers ----
    for (int L = 0; L < 5; L++) {
        const float* wl  = (const float*)d_in[7 + 4 * L];
        const float* wr  = (const float*)d_in[8 + 4 * L];
        const float* att = (const float*)d_in[9 + 4 * L];
        const float* gb  = (const float*)d_in[10 + 4 * L];
        int Fin = (L == 0) ? 512 : 1024;
        int HC  = (L == 4) ? 512 : 1024;
        const bf16* hin = (L == 0) ? b_resb : b_hb;

        transpose_f2b2<<<dim3(HC / 32, Fin / 32, 2), blk, 0, stream>>>(
            wl, b_wlb, wr, b_wrb, Fin, HC);
        gemm_mfma_bt<<<dim3(HC / 128, NN / 128), blk, 0, stream>>>(
            hin, b_wlb, (const float*)nullptr, (float*)nullptr, b_xlb,
            NN, HC, Fin, 0.f, 0);
        gemm_mfma_bt<<<dim3(HC / 128, NN / 128), blk, 0, stream>>>(
            hin, b_wrb, (const float*)nullptr, (float*)nullptr, b_xrb,
            NN, HC, Fin, 0.f, 0);
        if (L == 4) {
            gat_wave<512><<<NN / 4, blk, 0, stream>>>(
                b_xlb, b_xrb, att, gb, i_rs, i_src,
                b_res, b_h, (bf16*)nullptr, f_sums);
        } else {
            gat_wave<1024><<<NN / 4, blk, 0, stream>>>(
                b_xlb, b_xrb, att, gb, i_rs, i_src,
                (const float*)nullptr, (float*)nullptr, b_hb, (float*)nullptr);
        }
    }

    // ---- graph LN + softmax aggregation (single pass + combine) ----
    aggr_partial<<<dim3(BBG, 2, 4), blk, 0, stream>>>(
        b_h, f_sums, ln_w, ln_b, aggr_t, f_pm, f_pd, f_pa);
    aggr_combine<<<dim3(BBG, 2), blk, 0, stream>>>(f_pm, f_pd, f_pa, b_g);

    // ---- head MLP 512 -> 384 -> 256 -> 128 (fp32) ----
    gemm_f32<<<dim3(384 / 64, 1), blk, 0, stream>>>(
        b_g, m_w1, m_b1, b_m1, 64, 384, 512, 0.01f, 1);
    gemm_f32<<<dim3(256 / 64, 1), blk, 0, stream>>>(
        b_m1, m_w2, m_b2, b_m2, 64, 256, 384, 0.01f, 1);
    gemm_f32<<<dim3(128 / 64, 1), blk, 0, stream>>>(
        b_m2, m_w3, m_b3, out, 64, 128, 256, 0.f, 0);
}

// Round 7
// 1041.186 us; speedup vs baseline: 1.7126x; 1.1159x over previous
//
#include <hip/hip_runtime.h>
#include <hip/hip_bf16.h>

typedef __hip_bfloat16 bf16;

#define NN 16384          // gate nodes
#define BBG 64            // graphs
#define EE 49152          // directed edges (no self loops)
#define ET (EE + NN)      // edges + self loops = 65536
#define DD 512            // node feature dim (2F)
#define NG (NN / BBG)     // 256 nodes per graph

__device__ __forceinline__ float b2f(bf16 v) { return __bfloat162float(v); }
__device__ __forceinline__ bf16 f2b(float v) { return __float2bfloat16(v); }
__device__ __forceinline__ float sb2f(short s) {
    unsigned u = ((unsigned)(unsigned short)s) << 16;
    return __builtin_bit_cast(float, u);
}
__device__ __forceinline__ short f2bs(float v) {
    bf16 b = f2b(v);
    return __builtin_bit_cast(short, b);
}
__device__ __forceinline__ int clampi(int v, int lo, int hi)
{
    return v < lo ? lo : (v > hi ? hi : v);
}

typedef __attribute__((ext_vector_type(8))) short bf16x8;  // 8 bf16 = 4 VGPRs
typedef __attribute__((ext_vector_type(4))) float f32x4;

#define AS1 __attribute__((address_space(1)))
#define AS3 __attribute__((address_space(3)))

// ---------------------------------------------------------------------------
// MFMA bf16 GEMM (m97 structure): C[M,N] = act(A[M,K] @ Bt[N,K]^T + bias).
// Used for x_trans (bias + act + dual fp32/bf16 out).
// ---------------------------------------------------------------------------
__global__ __launch_bounds__(256) void gemm_mfma_bt(
    const bf16* __restrict__ A, const bf16* __restrict__ Bt,
    const float* __restrict__ bias, float* __restrict__ C,
    bf16* __restrict__ Cb, int M, int N, int K, float slope, int has_act)
{
    __shared__ bf16 As[128 * 32];
    __shared__ bf16 Bs[128 * 32];
    const int tid = threadIdx.x;
    const int w = tid >> 6;
    const int l = tid & 63;
    const int bm = blockIdx.y * 128;
    const int bn = blockIdx.x * 128;
    const int wrow = (w >> 1) * 64;
    const int wcol = (w & 1) * 64;
    const int quad = l >> 4;
    const int c16 = l & 15;

    const int lrow = l >> 2;
    const int lchunk = l & 3;
    const bf16* Ag = A + (size_t)(bm + w * 16 + lrow) * K + lchunk * 8;
    const bf16* Bg = Bt + (size_t)(bn + w * 16 + lrow) * K + lchunk * 8;
    char* AsB = (char*)As;
    char* BsB = (char*)Bs;

    f32x4 acc[4][4] = {};

    for (int k0 = 0; k0 < K; k0 += 32) {
        __builtin_amdgcn_global_load_lds((const AS1 void*)(Ag + k0),
            (AS3 void*)(AsB + w * 1024), 16, 0, 0);
        __builtin_amdgcn_global_load_lds((const AS1 void*)(Ag + (size_t)64 * K + k0),
            (AS3 void*)(AsB + 4096 + w * 1024), 16, 0, 0);
        __builtin_amdgcn_global_load_lds((const AS1 void*)(Bg + k0),
            (AS3 void*)(BsB + w * 1024), 16, 0, 0);
        __builtin_amdgcn_global_load_lds((const AS1 void*)(Bg + (size_t)64 * K + k0),
            (AS3 void*)(BsB + 4096 + w * 1024), 16, 0, 0);
        __syncthreads();

        bf16x8 a[4], b[4];
#pragma unroll
        for (int i = 0; i < 4; i++) {
            int ra = wrow + i * 16 + c16;
            a[i] = *(const bf16x8*)(AsB + ra * 64 + quad * 16);
            int rb = wcol + i * 16 + c16;
            b[i] = *(const bf16x8*)(BsB + rb * 64 + quad * 16);
        }
#pragma unroll
        for (int i = 0; i < 4; i++)
#pragma unroll
            for (int j = 0; j < 4; j++)
                acc[i][j] = __builtin_amdgcn_mfma_f32_16x16x32_bf16(
                    a[i], b[j], acc[i][j], 0, 0, 0);
        __syncthreads();
    }

#pragma unroll
    for (int i = 0; i < 4; i++) {
#pragma unroll
        for (int j = 0; j < 4; j++) {
            int col = bn + wcol + j * 16 + c16;
            float bv = bias ? bias[col] : 0.f;
#pragma unroll
            for (int r = 0; r < 4; r++) {
                int row = bm + wrow + i * 16 + quad * 4 + r;
                float v = acc[i][j][r] + bv;
                if (has_act) v = (v >= 0.f) ? v : v * slope;
                if (C)  C[(size_t)row * N + col] = v;
                if (Cb) Cb[(size_t)row * N + col] = f2b(v);
            }
        }
    }
}

// ---------------------------------------------------------------------------
// Merged dual GEMM: Bt = [wlT; wrT] (Ntot=2*HC rows). cols [0,HC) -> X0 (xl),
// cols [HC,2HC) -> X1 (xr). No bias/act. Halves dispatches + A-tile fetches.
// ---------------------------------------------------------------------------
__global__ __launch_bounds__(256) void gemm_mfma_dual(
    const bf16* __restrict__ A, const bf16* __restrict__ Bt,
    bf16* __restrict__ X0, bf16* __restrict__ X1,
    int M, int Ntot, int K, int HC)
{
    __shared__ bf16 As[128 * 32];
    __shared__ bf16 Bs[128 * 32];
    const int tid = threadIdx.x;
    const int w = tid >> 6;
    const int l = tid & 63;
    const int bm = blockIdx.y * 128;
    const int bn = blockIdx.x * 128;
    const int wrow = (w >> 1) * 64;
    const int wcol = (w & 1) * 64;
    const int quad = l >> 4;
    const int c16 = l & 15;

    const int lrow = l >> 2;
    const int lchunk = l & 3;
    const bf16* Ag = A + (size_t)(bm + w * 16 + lrow) * K + lchunk * 8;
    const bf16* Bg = Bt + (size_t)(bn + w * 16 + lrow) * K + lchunk * 8;
    char* AsB = (char*)As;
    char* BsB = (char*)Bs;

    f32x4 acc[4][4] = {};

    for (int k0 = 0; k0 < K; k0 += 32) {
        __builtin_amdgcn_global_load_lds((const AS1 void*)(Ag + k0),
            (AS3 void*)(AsB + w * 1024), 16, 0, 0);
        __builtin_amdgcn_global_load_lds((const AS1 void*)(Ag + (size_t)64 * K + k0),
            (AS3 void*)(AsB + 4096 + w * 1024), 16, 0, 0);
        __builtin_amdgcn_global_load_lds((const AS1 void*)(Bg + k0),
            (AS3 void*)(BsB + w * 1024), 16, 0, 0);
        __builtin_amdgcn_global_load_lds((const AS1 void*)(Bg + (size_t)64 * K + k0),
            (AS3 void*)(BsB + 4096 + w * 1024), 16, 0, 0);
        __syncthreads();

        bf16x8 a[4], b[4];
#pragma unroll
        for (int i = 0; i < 4; i++) {
            int ra = wrow + i * 16 + c16;
            a[i] = *(const bf16x8*)(AsB + ra * 64 + quad * 16);
            int rb = wcol + i * 16 + c16;
            b[i] = *(const bf16x8*)(BsB + rb * 64 + quad * 16);
        }
#pragma unroll
        for (int i = 0; i < 4; i++)
#pragma unroll
            for (int j = 0; j < 4; j++)
                acc[i][j] = __builtin_amdgcn_mfma_f32_16x16x32_bf16(
                    a[i], b[j], acc[i][j], 0, 0, 0);
        __syncthreads();
    }

#pragma unroll
    for (int i = 0; i < 4; i++) {
#pragma unroll
        for (int j = 0; j < 4; j++) {
            int col = bn + wcol + j * 16 + c16;
            bf16* dst = (col < HC) ? (X0 + col) : (X1 + col - HC);
#pragma unroll
            for (int r = 0; r < 4; r++) {
                int row = bm + wrow + i * 16 + quad * 4 + r;
                dst[(size_t)row * HC] = f2b(acc[i][j][r]);
            }
        }
    }
}

// ---------------------------------------------------------------------------
// fp32 GEMM (head MLP only)
// ---------------------------------------------------------------------------
__global__ __launch_bounds__(256) void gemm_f32(
    const float* __restrict__ A, const float* __restrict__ W,
    const float* __restrict__ bias, float* __restrict__ C,
    int M, int N, int K, float slope, int has_act)
{
    const int BK = 16;
    __shared__ float Asm[BK][64 + 1];
    __shared__ float Wsm[BK][64 + 1];
    int tid = threadIdx.x;
    int bm = blockIdx.y * 64;
    int bn = blockIdx.x * 64;
    int tr = tid >> 4;
    int tc = tid & 15;
    float acc[4][4] = {};

    for (int k0 = 0; k0 < K; k0 += BK) {
        {
            int col = tid & 15;
            int row = tid >> 4;
#pragma unroll
            for (int p = 0; p < 4; p++) {
                int r = row + p * 16;
                Asm[col][r] = A[(size_t)(bm + r) * K + k0 + col];
            }
        }
        {
            int wc = tid & 63;
            int wr = tid >> 6;
#pragma unroll
            for (int p = 0; p < 4; p++) {
                int r = wr + p * 4;
                Wsm[r][wc] = W[(size_t)(k0 + r) * N + bn + wc];
            }
        }
        __syncthreads();
#pragma unroll
        for (int kk = 0; kk < BK; kk++) {
            float a[4], w[4];
#pragma unroll
            for (int i = 0; i < 4; i++) a[i] = Asm[kk][tr * 4 + i];
#pragma unroll
            for (int j = 0; j < 4; j++) w[j] = Wsm[kk][tc * 4 + j];
#pragma unroll
            for (int i = 0; i < 4; i++)
#pragma unroll
                for (int j = 0; j < 4; j++)
                    acc[i][j] += a[i] * w[j];
        }
        __syncthreads();
    }
#pragma unroll
    for (int i = 0; i < 4; i++) {
        int r = bm + tr * 4 + i;
#pragma unroll
        for (int j = 0; j < 4; j++) {
            int cn = bn + tc * 4 + j;
            float v = acc[i][j];
            if (bias) v += bias[cn];
            if (has_act) v = (v >= 0.f) ? v : v * slope;
            C[(size_t)r * N + cn] = v;
        }
    }
}

// ---------------------------------------------------------------------------
// Batched fp32 [R,C] -> bf16 [C,R] transpose-convert (z selects tensor pair)
// ---------------------------------------------------------------------------
__global__ __launch_bounds__(256) void transpose_f2b2(
    const float* __restrict__ in0, bf16* __restrict__ out0,
    const float* __restrict__ in1, bf16* __restrict__ out1, int R, int C)
{
    const float* in = blockIdx.z ? in1 : in0;
    bf16* out = blockIdx.z ? out1 : out0;
    __shared__ float tile[32][33];
    int c0 = blockIdx.x * 32;
    int r0 = blockIdx.y * 32;
    int tx = threadIdx.x & 31;
    int ty = threadIdx.x >> 5;
#pragma unroll
    for (int k = 0; k < 4; k++) {
        int r = ty + k * 8;
        tile[r][tx] = in[(size_t)(r0 + r) * C + c0 + tx];
    }
    __syncthreads();
#pragma unroll
    for (int k = 0; k < 4; k++) {
        int rr = ty + k * 8;
        out[(size_t)(c0 + rr) * R + r0 + tx] = f2b(tile[tx][rr]);
    }
}

__global__ void f2b_vec(const float* __restrict__ in, bf16* __restrict__ out, int n)
{
    int i = blockIdx.x * 256 + threadIdx.x;
    if (i < n) out[i] = f2b(in[i]);
}

// ---------------------------------------------------------------------------
// CSR build over dst (self loops: edge ids [EE, ET) are node e-EE)
// ---------------------------------------------------------------------------
__global__ void count_deg(const int* __restrict__ ei, int* __restrict__ deg)
{
    int e = blockIdx.x * 256 + threadIdx.x;
    if (e >= ET) return;
    int d = (e < EE) ? ei[EE + e] : (e - EE);
    d = clampi(d, 0, NN - 1);
    atomicAdd(&deg[d], 1);
}

__global__ __launch_bounds__(256) void scan_deg(const int* __restrict__ deg,
                                                int* __restrict__ rs)
{
    __shared__ int part[256];
    __shared__ int psum[257];
    int tid = threadIdx.x;
    const int per = NN / 256;
    int base = tid * per;
    int s = 0;
    for (int i = 0; i < per; i++) s += deg[base + i];
    part[tid] = s;
    __syncthreads();
    if (tid == 0) {
        int acc = 0;
        for (int i = 0; i < 256; i++) { psum[i] = acc; acc += part[i]; }
        psum[256] = acc;
    }
    __syncthreads();
    int acc = psum[tid];
    for (int i = 0; i < per; i++) { rs[base + i] = acc; acc += deg[base + i]; }
    if (tid == 0) rs[NN] = psum[256];
}

__global__ void fill_csr(const int* __restrict__ ei, const int* __restrict__ rs,
                         int* __restrict__ cur, int* __restrict__ csrc)
{
    int e = blockIdx.x * 256 + threadIdx.x;
    if (e >= ET) return;
    int s, d;
    if (e < EE) { s = ei[e]; d = ei[EE + e]; } else { s = d = e - EE; }
    s = clampi(s, 0, NN - 1);
    d = clampi(d, 0, NN - 1);
    int pos = atomicAdd(&cur[d], 1);
    int slot = clampi(rs[d] + pos, 0, ET - 1);
    csrc[slot] = s;
}

// ---------------------------------------------------------------------------
// GATv2 edge phase v4: wave-per-node, online softmax, and MAX MEMORY-LEVEL
// PARALLELISM: first PF=6 gathered rows loaded up-front into a statically
// indexed register array (12 independent dwordx4 per lane in flight), rare
// deg>PF tail streams with 1-ahead prefetch. launch_bounds(256,4) pins
// <=128 VGPRs so occupancy stays 4 waves/SIMD.
// ---------------------------------------------------------------------------
template<int HC>
__global__ __launch_bounds__(256, 4) void gat_wave2(
    const bf16* __restrict__ xl, const bf16* __restrict__ xr,
    const float* __restrict__ att, const float* __restrict__ bias,
    const int* __restrict__ rs, const int* __restrict__ csrc,
    const float* __restrict__ res, float* __restrict__ out_f,
    bf16* __restrict__ out_b, float* __restrict__ lnsums)
{
    constexpr int CPL = HC / 64;     // channels per lane (16 or 8)
    constexpr int NV = CPL / 8;      // bf16x8 vectors per lane (2 or 1)
    constexpr int PF = 6;            // rows prefetched into registers
    const int tid = threadIdx.x;
    const int w = tid >> 6;
    const int lane = tid & 63;
    const int n = blockIdx.x * 4 + w;
    const int c0 = lane * CPL;

    int start = rs[n];
    int deg = clampi(rs[n + 1] - start, 1, 64);
    start = clampi(start, 0, ET - 1);
    int my_src = 0;
    if (lane < deg) my_src = clampi(csrc[start + lane], 0, NN - 1);

    // preload att + xr chunk into registers (reused across all edges)
    float av[CPL], rv[CPL];
    {
        bf16x8 rp[NV];
#pragma unroll
        for (int v = 0; v < NV; v++)
            rp[v] = *(const bf16x8*)(xr + (size_t)n * HC + c0 + v * 8);
#pragma unroll
        for (int k = 0; k < CPL; k++) {
            rv[k] = sb2f(rp[k / 8][k % 8]);
            av[k] = att[c0 + k];
        }
    }

    // prefetch first PF rows (all loads independent -> in flight together)
    bf16x8 rows[PF][NV];
#pragma unroll
    for (int r = 0; r < PF; r++) {
        if (r < deg) {
            int s = __shfl(my_src, r);
            const bf16* rp = xl + (size_t)s * HC + c0;
#pragma unroll
            for (int v = 0; v < NV; v++) rows[r][v] = *(const bf16x8*)(rp + v * 8);
        }
    }

    float m = -1e30f, den = 0.f;
    float acc[CPL];
#pragma unroll
    for (int k = 0; k < CPL; k++) acc[k] = 0.f;

    auto process = [&](bf16x8 (&rw)[NV]) {
        float part = 0.f;
#pragma unroll
        for (int k = 0; k < CPL; k++) {
            float x = sb2f(rw[k / 8][k % 8]);
            float u = x + rv[k];
            u = (u >= 0.f) ? u : 0.2f * u;
            part = fmaf(av[k], u, part);
        }
        if (HC == 1024) {
#pragma unroll
            for (int msk = 16; msk; msk >>= 1) part += __shfl_xor(part, msk);
        } else {
#pragma unroll
            for (int msk = 32; msk; msk >>= 1) part += __shfl_xor(part, msk);
        }
        float lg = part;
        float mn = fmaxf(m, lg);
        float r = __expf(m - mn);
        float pi = __expf(lg - mn);
        m = mn;
        den = den * r + pi;
#pragma unroll
        for (int k = 0; k < CPL; k++) {
            float x = sb2f(rw[k / 8][k % 8]);
            acc[k] = fmaf(acc[k], r, pi * x);
        }
    };

#pragma unroll
    for (int i = 0; i < PF; i++)
        if (i < deg) process(rows[i]);

    if (deg > PF) {   // rare tail (~8% of nodes): stream with 1-ahead prefetch
        bf16x8 curv[NV], nxt[NV];
        {
            int s = __shfl(my_src, PF);
            const bf16* rp = xl + (size_t)s * HC + c0;
#pragma unroll
            for (int v = 0; v < NV; v++) curv[v] = *(const bf16x8*)(rp + v * 8);
        }
        for (int i = PF; i < deg; i++) {
            if (i + 1 < deg) {
                int s = __shfl(my_src, i + 1);
                const bf16* rp = xl + (size_t)s * HC + c0;
#pragma unroll
                for (int v = 0; v < NV; v++) nxt[v] = *(const bf16x8*)(rp + v * 8);
            }
            process(curv);
#pragma unroll
            for (int v = 0; v < NV; v++) curv[v] = nxt[v];
        }
    }

    float inv = 1.f / den;
    float ls = 0.f, ls2 = 0.f;
    float vals[CPL];
#pragma unroll
    for (int k = 0; k < CPL; k++) {
        float v = fmaf(acc[k], inv, bias[c0 + k]);
        v = (v >= 0.f) ? v : 0.01f * v;
        vals[k] = v;
    }
    if (res) {   // L4: residual add, fp32 out, LN sums
#pragma unroll
        for (int k = 0; k < CPL; k++) {
            vals[k] += res[(size_t)n * HC + c0 + k];
            ls += vals[k];
            ls2 += vals[k] * vals[k];
        }
#pragma unroll
        for (int v = 0; v < NV * 2; v++) {
            f32x4 ov;
#pragma unroll
            for (int k = 0; k < 4; k++) ov[k] = vals[v * 4 + k];
            *(f32x4*)(out_f + (size_t)n * HC + c0 + v * 4) = ov;
        }
    } else {     // L0-3: bf16 out
#pragma unroll
        for (int v = 0; v < NV; v++) {
            bf16x8 ov;
#pragma unroll
            for (int k = 0; k < 8; k++) ov[k] = f2bs(vals[v * 8 + k]);
            *(bf16x8*)(out_b + (size_t)n * HC + c0 + v * 8) = ov;
        }
    }

    if (lnsums) {
#pragma unroll
        for (int msk = 32; msk; msk >>= 1) {
            ls += __shfl_xor(ls, msk);
            ls2 += __shfl_xor(ls2, msk);
        }
        if (lane == 0) {
            int g = n >> 8;
            atomicAdd(&lnsums[g], ls);
            atomicAdd(&lnsums[BBG + g], ls2);
        }
    }
}

// ---------------------------------------------------------------------------
// LN apply + channel-wise online-softmax aggregation, node-chunked partials.
// grid (BBG, 2, 8): graph, channel half, 32-node chunk.
// ---------------------------------------------------------------------------
__global__ __launch_bounds__(256) void aggr_partial(
    const float* __restrict__ h, const float* __restrict__ lnsums,
    const float* __restrict__ lnw, const float* __restrict__ lnb,
    const float* __restrict__ t_, float* __restrict__ pm,
    float* __restrict__ pd, float* __restrict__ pa)
{
    int g = blockIdx.x, ch = blockIdx.y, nk = blockIdx.z;
    int tid = threadIdx.x;
    int c = ch * 256 + tid;
    const float tot = (float)(NG * DD);
    float S = lnsums[g], S2 = lnsums[BBG + g];
    float mu = S / tot;
    float iv = rsqrtf(fmaxf(S2 / tot - mu * mu, 0.f) + 1e-5f);
    float w = lnw[c], b = lnb[c], t = t_[0];
    size_t base = (size_t)g * NG * DD + (size_t)nk * 32 * DD + c;
    float m = -1e30f, den = 0.f, acc = 0.f;
    for (int i = 0; i < 32; i++) {
        float hn = (h[base + (size_t)i * DD] - mu) * iv * w + b;
        float lg = hn * t;
        if (lg > m) {
            float r = __expf(m - lg);
            den *= r; acc *= r; m = lg;
        }
        float p = __expf(lg - m);
        den += p; acc += p * hn;
    }
    size_t idx = (((size_t)g * 2 + ch) * 8 + nk) * 256 + tid;
    pm[idx] = m; pd[idx] = den; pa[idx] = acc;
}

__global__ __launch_bounds__(256) void aggr_combine(
    const float* __restrict__ pm, const float* __restrict__ pd,
    const float* __restrict__ pa, float* __restrict__ gout)
{
    int g = blockIdx.x, ch = blockIdx.y;
    int tid = threadIdx.x;
    size_t base = (((size_t)g * 2 + ch) * 8) * 256 + tid;
    float m = -1e30f;
#pragma unroll
    for (int k = 0; k < 8; k++) m = fmaxf(m, pm[base + k * 256]);
    float den = 0.f, acc = 0.f;
#pragma unroll
    for (int k = 0; k < 8; k++) {
        float r = __expf(pm[base + k * 256] - m);
        den += pd[base + k * 256] * r;
        acc += pa[base + k * 256] * r;
    }
    gout[(size_t)g * DD + ch * 256 + tid] = acc / den;
}

// ---------------------------------------------------------------------------
extern "C" void kernel_launch(void* const* d_in, const int* in_sizes, int n_in,
                              void* d_out, int out_size, void* d_ws, size_t ws_size,
                              hipStream_t stream)
{
    const float* x      = (const float*)d_in[0];
    const int*   ei     = (const int*)d_in[1];
    const float* xt_w1  = (const float*)d_in[3];
    const float* xt_b1  = (const float*)d_in[4];
    const float* xt_w2  = (const float*)d_in[5];
    const float* xt_b2  = (const float*)d_in[6];
    const float* ln_w   = (const float*)d_in[27];
    const float* ln_b   = (const float*)d_in[28];
    const float* aggr_t = (const float*)d_in[29];
    const float* m_w1   = (const float*)d_in[30];
    const float* m_b1   = (const float*)d_in[31];
    const float* m_w2   = (const float*)d_in[32];
    const float* m_b2   = (const float*)d_in[33];
    const float* m_w3   = (const float*)d_in[34];
    const float* m_b3   = (const float*)d_in[35];
    float* out = (float*)d_out;

    // ---- workspace layout (256B aligned); ints first ----
    char* p = (char*)d_ws;
    auto take = [&](size_t bytes) {
        char* r = p;
        p += (bytes + 255) & ~(size_t)255;
        return r;
    };
    int* i_deg     = (int*)take((size_t)(NN + 1) * 4);
    int* i_rs      = (int*)take((size_t)(NN + 1) * 4);
    int* i_cur     = (int*)take((size_t)NN * 4);
    int* i_src     = (int*)take((size_t)ET * 4);
    float* f_sums  = (float*)take((size_t)2 * BBG * 4);
    float* f_pm    = (float*)take((size_t)BBG * 2 * 8 * 256 * 4);
    float* f_pd    = (float*)take((size_t)BBG * 2 * 8 * 256 * 4);
    float* f_pa    = (float*)take((size_t)BBG * 2 * 8 * 256 * 4);
    float* b_g     = (float*)take((size_t)BBG * DD * 4);
    float* b_m1    = (float*)take((size_t)BBG * 384 * 4);
    float* b_m2    = (float*)take((size_t)BBG * 256 * 4);
    float* b_res   = (float*)take((size_t)NN * DD * 4);
    float* b_h     = (float*)take((size_t)NN * DD * 4);
    bf16* b_resb   = (bf16*)take((size_t)NN * DD * 2);
    bf16* b_hb     = (bf16*)take((size_t)NN * 1024 * 2);
    bf16* b_xlb    = (bf16*)take((size_t)NN * 1024 * 2);
    bf16* b_xrb    = (bf16*)take((size_t)NN * 1024 * 2);
    bf16* b_xb     = (bf16*)take((size_t)2 * NN * 32 * 2);
    bf16* b_wcat   = (bf16*)take((size_t)2048 * 1024 * 2);  // [wlT; wrT]
    bf16* b_w1b    = (bf16*)take((size_t)32 * 256 * 2);
    bf16* b_w2b    = (bf16*)take((size_t)256 * 256 * 2);
    bf16* b_t1b = b_hb;

    dim3 blk(256);

    // ---- CSR build + LN-sum zero ----
    hipMemsetAsync(i_deg, 0, (size_t)(NN + 1) * 4, stream);
    hipMemsetAsync(i_cur, 0, (size_t)NN * 4, stream);
    hipMemsetAsync(f_sums, 0, (size_t)2 * BBG * 4, stream);
    count_deg<<<ET / 256, blk, 0, stream>>>(ei, i_deg);
    scan_deg<<<1, blk, 0, stream>>>(i_deg, i_rs);
    fill_csr<<<ET / 256, blk, 0, stream>>>(ei, i_rs, i_cur, i_src);

    // ---- weight converts for x_trans + x convert ----
    f2b_vec<<<(2 * NN * 32 + 255) / 256, blk, 0, stream>>>(x, b_xb, 2 * NN * 32);
    transpose_f2b2<<<dim3(256 / 32, 32 / 32, 1), blk, 0, stream>>>(
        xt_w1, b_w1b, xt_w1, b_w1b, 32, 256);
    transpose_f2b2<<<dim3(256 / 32, 256 / 32, 1), blk, 0, stream>>>(
        xt_w2, b_w2b, xt_w2, b_w2b, 256, 256);

    // ---- x_trans ----
    gemm_mfma_bt<<<dim3(256 / 128, 32768 / 128), blk, 0, stream>>>(
        b_xb, b_w1b, xt_b1, (float*)nullptr, b_t1b, 32768, 256, 32, 0.01f, 1);
    gemm_mfma_bt<<<dim3(256 / 128, 32768 / 128), blk, 0, stream>>>(
        b_t1b, b_w2b, xt_b2, b_res, b_resb, 32768, 256, 256, 0.f, 0);

    // ---- 5 GATv2 layers ----
    for (int L = 0; L < 5; L++) {
        const float* wl  = (const float*)d_in[7 + 4 * L];
        const float* wr  = (const float*)d_in[8 + 4 * L];
        const float* att = (const float*)d_in[9 + 4 * L];
        const float* gb  = (const float*)d_in[10 + 4 * L];
        int Fin = (L == 0) ? 512 : 1024;
        int HC  = (L == 4) ? 512 : 1024;
        const bf16* hin = (L == 0) ? b_resb : b_hb;

        transpose_f2b2<<<dim3(HC / 32, Fin / 32, 2), blk, 0, stream>>>(
            wl, b_wcat, wr, b_wcat + (size_t)HC * Fin, Fin, HC);
        gemm_mfma_dual<<<dim3(2 * HC / 128, NN / 128), blk, 0, stream>>>(
            hin, b_wcat, b_xlb, b_xrb, NN, 2 * HC, Fin, HC);
        if (L == 4) {
            gat_wave2<512><<<NN / 4, blk, 0, stream>>>(
                b_xlb, b_xrb, att, gb, i_rs, i_src,
                b_res, b_h, (bf16*)nullptr, f_sums);
        } else {
            gat_wave2<1024><<<NN / 4, blk, 0, stream>>>(
                b_xlb, b_xrb, att, gb, i_rs, i_src,
                (const float*)nullptr, (float*)nullptr, b_hb, (float*)nullptr);
        }
    }

    // ---- graph LN + softmax aggregation (single pass + combine) ----
    aggr_partial<<<dim3(BBG, 2, 8), blk, 0, stream>>>(
        b_h, f_sums, ln_w, ln_b, aggr_t, f_pm, f_pd, f_pa);
    aggr_combine<<<dim3(BBG, 2), blk, 0, stream>>>(f_pm, f_pd, f_pa, b_g);

    // ---- head MLP 512 -> 384 -> 256 -> 128 (fp32) ----
    gemm_f32<<<dim3(384 / 64, 1), blk, 0, stream>>>(
        b_g, m_w1, m_b1, b_m1, 64, 384, 512, 0.01f, 1);
    gemm_f32<<<dim3(256 / 64, 1), blk, 0, stream>>>(
        b_m1, m_w2, m_b2, b_m2, 64, 256, 384, 0.01f, 1);
    gemm_f32<<<dim3(128 / 64, 1), blk, 0, stream>>>(
        b_m2, m_w3, m_b3, out, 64, 128, 256, 0.f, 0);
}